// Round 4
// baseline (415.065 us; speedup 1.0000x reference)
//
#include <hip/hip_runtime.h>
#include <hip/hip_bf16.h>

// TMDConv (PaiNN/TorchMD-style) two-pass message passing on MI355X.
// R15 changes vs R14 (R14: 226us NEUTRAL — final_kernel's 36MB uvbuf/vnew
// round-trip + hidden_kernel's 2B-partial-store RMW ate the savings):
//  - hidden fused INTO pass1 epilogue: block holds all 128 snew features ->
//    LDS broadcast + split-K bf16 dot -> h; vnew4 {v0,v1,v2,h} written once
//    (kills hidden dispatch, RMW stores, snbf buffer).
//  - final fused INTO pass2 epilogue: block holds uv/hmean -> LDS broadcast
//    + split-K dots vs w_us2 -> s_mean; norm+outputs in-place (kills final
//    dispatch + uvbuf/hmean ~36MB round-trip).
//  - phase-B pad slots: loads stay unconditional/batched (regs, latency
//    hiding) but unpack+FMA guarded by wave-uniform el<bcnt (~37% of slot
//    work was zero-padding at avg deg 10). Au/Wl/Asn pad-zeroing dropped
//    (pads unread; MFMA garbage only reaches discarded acc rows).
//  Pipeline: 6 -> 4 dispatches.

#define F_DIM   128
#define F3_DIM  384
#define L_DIM   20
#define CAP     64          // max in-degree bucket capacity
#define BATCH   16

typedef __attribute__((ext_vector_type(8))) short short8;
typedef __attribute__((ext_vector_type(4))) float f32x4;
typedef __attribute__((ext_vector_type(4))) unsigned short us4;

struct u3 { unsigned a, b, c; };   // 12B record (dwordx3)

__device__ __forceinline__ unsigned short f2bf(float f) {
  union { float f; unsigned u; } a; a.f = f;
  unsigned u = a.u;
  u = (u + 0x7FFFu + ((u >> 16) & 1u)) >> 16;   // RNE
  return (unsigned short)u;
}
__device__ __forceinline__ float bf2f(unsigned short u) {
  union { unsigned u; float f; } a; a.u = ((unsigned)u) << 16;
  return a.f;
}

// ---------------------------------------------------------------------------
// fused cast+fill kernel (+ zeroing of combo1 / vnew4 pad rows)
__global__ __launch_bounds__(256) void cast_fill_kernel(
    const float* __restrict__ ms1_w, unsigned short* __restrict__ w_ms1,
    const float* __restrict__ ms2_w, unsigned short* __restrict__ w_ms2,
    const float* __restrict__ us1_w, unsigned short* __restrict__ w_us1,
    const float* __restrict__ us2_w, unsigned short* __restrict__ w_us2,
    const float* __restrict__ s,     unsigned short* __restrict__ sbf,
    const float* __restrict__ v,     us4* __restrict__ v4,
    const float* __restrict__ mv_w,  unsigned short* __restrict__ mvwB,
    const int* __restrict__ src, const int* __restrict__ dst,
    int* __restrict__ cursor, int* __restrict__ jbuf,
    unsigned short* __restrict__ c1pad, unsigned short* __restrict__ v4pad,
    int nF, int E)
{
  int i = blockIdx.x * 256 + threadIdx.x;
  if (i < 16384) w_ms1[i] = f2bf(ms1_w[i]);
  if (i < 49152) w_ms2[i] = f2bf(ms2_w[i]);
  if (i < 16384) w_us1[i] = f2bf(us1_w[i]);
  if (i < 49152) w_us2[i] = f2bf(us2_w[i]);
  if (i < nF)    sbf[i] = f2bf(s[i]);
  if (i < nF) {
    const float* vp = v + (size_t)i * 3;
    us4 o; o.x = f2bf(vp[0]); o.y = f2bf(vp[1]); o.z = f2bf(vp[2]); o.w = 0;
    v4[i] = o;
  }
  if (i < 384 * 32) {
    int o = i >> 5, k = i & 31;
    float val = (k < 20) ? mv_w[o * 20 + k] * 0.6324555320336759f : 0.f;
    mvwB[i] = f2bf(val);
  }
  if (i < 768) c1pad[i] = 0;   // combo1 dummy row (pad loads, values unread)
  if (i < 512) v4pad[i] = 0;   // vnew4  dummy row
  if (i < E) {
    int d = dst[i];
    int p = atomicAdd(&cursor[d], 1);
    if (p < CAP) jbuf[d * CAP + p] = src[i];
  }
}

// ---------------------------------------------------------------------------
// Yc[n][f] (12B) = { (ssp(X@W1^T+b1)@W2^T+b2) triplet , Vin[n][f] triplet }
// 8 waves per block, 16 nodes per block; wave w owns feature-tile t = w.
__global__ __launch_bounds__(512) void mlp_kernel(
    const unsigned short* __restrict__ X,    // [n][128] bf16
    const unsigned short* __restrict__ W1,   // [128][128] bf16
    const float* __restrict__ B1,            // [128]
    const unsigned short* __restrict__ W2,   // [384][128] bf16
    const float* __restrict__ B2,            // [384]
    const us4* __restrict__ Vin,             // [n][128] bf16 triplet
    unsigned short* __restrict__ Yc)         // [n][128] 12B records
{
  __shared__ float HT[128 * 17];
  const int lane = threadIdx.x & 63;
  const int wave = threadIdx.x >> 6;         // 0..7 = feature tile
  const int c    = lane & 15;
  const int quad = lane >> 4;
  const int m0   = blockIdx.x * 16;

  // GEMM1: this wave's single output tile t = wave
  f32x4 acc = (f32x4){0.f, 0.f, 0.f, 0.f};
#pragma unroll
  for (int kk = 0; kk < 4; kk++) {
    short8 a = *(const short8*)(X + (size_t)(m0 + c) * 128 + kk * 32 + quad * 8);
    short8 b = *(const short8*)(W1 + (size_t)(wave * 16 + c) * 128 + kk * 32 + quad * 8);
    acc = __builtin_amdgcn_mfma_f32_16x16x32_bf16(a, b, acc, 0, 0, 0);
  }
  {
    int k = wave * 16 + c;
    float bias = B1[k];
#pragma unroll
    for (int r = 0; r < 4; r++) {
      float h = acc[r] + bias;
      float sp = (h > 15.f) ? h : log1pf(__expf(h));
      sp -= 0.69314718056f;
      HT[k * 17 + quad * 4 + r] = sp;
    }
  }
  __syncthreads();

  // GEMM2: 3 tiles (g=0..2) at t = wave, so the 12B record write stays fused
  f32x4 acc2[3];
#pragma unroll
  for (int g = 0; g < 3; g++) acc2[g] = (f32x4){0.f, 0.f, 0.f, 0.f};
#pragma unroll
  for (int kk = 0; kk < 4; kk++) {
    short8 afr;
#pragma unroll
    for (int j = 0; j < 8; j++) {
      float hv = HT[(kk * 32 + quad * 8 + j) * 17 + c];
      afr[j] = (short)f2bf(hv);
    }
#pragma unroll
    for (int g = 0; g < 3; g++) {
      short8 b = *(const short8*)(W2 + (size_t)(g * 128 + wave * 16 + c) * 128 + kk * 32 + quad * 8);
      acc2[g] = __builtin_amdgcn_mfma_f32_16x16x32_bf16(afr, b, acc2[g], 0, 0, 0);
    }
  }
  {
    int f = wave * 16 + c;                   // feature in [0,128)
    float b0 = B2[f], b1 = B2[128 + f], b2 = B2[256 + f];
#pragma unroll
    for (int r = 0; r < 4; r++) {
      int m = quad * 4 + r;
      us4 vv = Vin[(size_t)(m0 + m) * 128 + f];
      unsigned p0 = f2bf(acc2[0][r] + b0);
      unsigned p1 = f2bf(acc2[1][r] + b1);
      unsigned p2 = f2bf(acc2[2][r] + b2);
      u3 rec;
      rec.a = p0 | (p1 << 16);
      rec.b = p2 | ((unsigned)vv.x << 16);
      rec.c = (unsigned)vv.y | ((unsigned)vv.z << 16);
      *(u3*)(Yc + ((size_t)(m0 + m) * 128 + f) * 6) = rec;
    }
  }
}

// ---------------------------------------------------------------------------
// pass 1 (fused W-GEMM + fused hidden GEMV): block = 1 dst node,
// 4 waves = (feature half) x (edge parity). Epilogue computes
// h = ssp(snew@us1^T+b1) via LDS-broadcast split-K dot and writes the full
// vnew4 record {v0,v1,v2,h}.
__global__ __launch_bounds__(256, 4) void pass1_kernel(
    const float* __restrict__ x,       // [N,3]
    const unsigned short* __restrict__ combo1, // [N+1,128] 12B {phi012,v012}
    const float* __restrict__ v,       // [N,128,3] fp32 (epilogue add)
    const float* __restrict__ s,       // [N,128]
    const unsigned short* __restrict__ mvwB,  // [384][32] bf16 scale-folded
    const float* __restrict__ mv_b,           // [384]
    const unsigned short* __restrict__ wu1,   // [128][128] bf16 (us1_w)
    const float* __restrict__ bu1,            // [128] (us1_b)
    const int* __restrict__ jbuf,      // [N,CAP] src ids
    const int* __restrict__ deg,
    float* __restrict__ vnew, us4* __restrict__ vnew4,
    float* __restrict__ snew, int nNodes)
{
  __shared__ unsigned short Asn[BATCH * 32];  // 1 KB  A-tile (bf16 sn rows)
  __shared__ float4 Au[BATCH];                // 256 B {u0,u1,u2,invr}
  __shared__ us4 Wl[BATCH * 128];             // 16 KB per-batch weight triplets
  __shared__ float red[512];                  // 2 KB  cross-wave reduction
  __shared__ float SN[128];                   // snew (bf16-rounded) broadcast
  __shared__ float PH[128];                   // hidden-dot partials

  const int tid  = threadIdx.x;
  const int wave = tid >> 6, lane = tid & 63;
  const int half = wave >> 1, split = wave & 1;
  const int i = blockIdx.x;
  const int f = lane + 64 * half;             // feature in [0,128)
  const int c = lane & 15, quad = lane >> 4;

  int cnt = deg[i]; if (cnt > CAP) cnt = CAP;
  const int base = i * CAP;

  // B-frags + bias for this wave's 6 tiles: {2w,2w+1,2w+8,2w+9,2w+16,2w+17}
  short8 bfr[6]; float bias[6];
#pragma unroll
  for (int p = 0; p < 3; p++)
#pragma unroll
    for (int h = 0; h < 2; h++) {
      int t = 2 * wave + h + 8 * p;
      bfr[p * 2 + h]  = *(const short8*)(mvwB + (size_t)(t * 16 + c) * 32 + quad * 8);
      bias[p * 2 + h] = mv_b[t * 16 + c];
    }

  const float xi0 = x[i * 3], xi1 = x[i * 3 + 1], xi2 = x[i * 3 + 2];
  int jv = (lane < cnt) ? jbuf[base + lane] : nNodes;   // dummy row for pads

  float accV0 = 0.f, accV1 = 0.f, accV2 = 0.f, accS = 0.f;

  for (int bs = 0; bs < cnt; bs += BATCH) {
    int bcnt = cnt - bs; if (bcnt > BATCH) bcnt = BATCH;
    __syncthreads();                           // previous batch fully consumed

    if (wave == 0) {
      // ALL 64 lanes execute the shfl (source lanes must be exec-active);
      // e = bs + (lane&15) <= 48+15 = 63, always a valid source lane.
      int t16 = lane & (BATCH - 1);
      int e = bs + t16;
      int j = __shfl(jv, e);
      if (lane < BATCH && e < cnt) {
        float d0 = x[j * 3]     - xi0;
        float d1 = x[j * 3 + 1] - xi1;
        float d2 = x[j * 3 + 2] - xi2;
        float r = sqrtf(d0 * d0 + d1 * d1 + d2 * d2 + 1e-5f);
        float invr = 1.0f / r;
        Au[lane] = make_float4(d0 * invr, d1 * invr, d2 * invr, invr);
        float theta = r * 0.6283185307179586f;
        float s1, c1;
        __sincosf(theta, &s1, &c1);
        float c2 = 2.f * c1;
        float pm2 = s1, pm1 = c2 * s1;
        Asn[lane * 32 + 0] = f2bf(pm2);
        Asn[lane * 32 + 1] = f2bf(pm1);
#pragma unroll
        for (int l = 2; l < L_DIM; l++) {
          float cur = c2 * pm1 - pm2;
          Asn[lane * 32 + l] = f2bf(cur);
          pm2 = pm1; pm1 = cur;
        }
#pragma unroll
        for (int l = L_DIM; l < 32; l++) Asn[lane * 32 + l] = 0;
        // NOTE: pad rows (e >= cnt) left uninitialized on purpose — they
        // only feed MFMA acc rows that the el<bcnt guards discard.
      }
    }
    __syncthreads();

    // single 16-row MFMA group
    {
      short8 a = *(const short8*)&Asn[c * 32 + quad * 8];
      f32x4 acc[6];
#pragma unroll
      for (int q = 0; q < 6; q++)
        acc[q] = __builtin_amdgcn_mfma_f32_16x16x32_bf16(
            a, bfr[q], (f32x4){0.f, 0.f, 0.f, 0.f}, 0, 0, 0);
#pragma unroll
      for (int r = 0; r < 4; r++) {
        int el = quad * 4 + r;
        if (el < bcnt) {
          float invr = Au[el].w;
#pragma unroll
          for (int h = 0; h < 2; h++) {
            float wp0 = fmaf(acc[h][r],     invr, bias[h]);
            float wp1 = fmaf(acc[2 + h][r], invr, bias[2 + h]);
            float wp2 = fmaf(acc[4 + h][r], invr, bias[4 + h]);
            float w0 = (wp0 < 5.f) ? 0.5f * (__cosf(wp0 * 0.6283185307179586f) + 1.f) : 0.f;
            float w1 = (wp1 < 5.f) ? 0.5f * (__cosf(wp1 * 0.6283185307179586f) + 1.f) : 0.f;
            float w2 = (wp2 < 5.f) ? 0.5f * (__cosf(wp2 * 0.6283185307179586f) + 1.f) : 0.f;
            us4 o; o.x = f2bf(w0); o.y = f2bf(w1); o.z = f2bf(w2); o.w = 0;
            Wl[el * 128 + wave * 32 + h * 16 + c] = o;
          }
        }
      }
    }
    __syncthreads();

    // phase B: loads unconditional/batched (cb stays in registers, pads hit
    // the L1-hot dummy row); unpack+FMA guarded wave-uniformly (el, bcnt
    // uniform per wave) -> padded-slot VALU skipped.
    u3 cb[8];
#pragma unroll
    for (int k = 0; k < 8; k++) {
      int j = __shfl(jv, bs + split + 2 * k);
      cb[k] = *(const u3*)(combo1 + ((size_t)j * 128 + f) * 6);
    }
#pragma unroll
    for (int k = 0; k < 8; k++) {
      int el = split + 2 * k;
      if (el < bcnt) {
        float4 u = Au[el];
        us4 wv = Wl[el * 128 + f];
        float ph0 = bf2f((unsigned short)(cb[k].a & 0xffff));
        float ph1 = bf2f((unsigned short)(cb[k].a >> 16));
        float ph2 = bf2f((unsigned short)(cb[k].b & 0xffff));
        float vx  = bf2f((unsigned short)(cb[k].b >> 16));
        float vy  = bf2f((unsigned short)(cb[k].c & 0xffff));
        float vz  = bf2f((unsigned short)(cb[k].c >> 16));
        float m0 = ph0 * bf2f(wv.x);
        float m1 = ph1 * bf2f(wv.y);
        float m2 = ph2 * bf2f(wv.z);
        accV0 = fmaf(vx, m0, fmaf(m2, u.x, accV0));
        accV1 = fmaf(vy, m0, fmaf(m2, u.y, accV1));
        accV2 = fmaf(vz, m0, fmaf(m2, u.z, accV2));
        accS += m1;
      }
    }
  }

  const int idx = half * 64 + lane;           // == f
  __syncthreads();
  if (split == 1) {
    red[idx * 4 + 0] = accV0; red[idx * 4 + 1] = accV1;
    red[idx * 4 + 2] = accV2; red[idx * 4 + 3] = accS;
  }
  __syncthreads();
  float n0 = 0.f, n1 = 0.f, n2 = 0.f;
  if (split == 0) {
    accV0 += red[idx * 4 + 0]; accV1 += red[idx * 4 + 1];
    accV2 += red[idx * 4 + 2]; accS  += red[idx * 4 + 3];
    size_t b3 = (size_t)i * 384 + f * 3;
    n0 = v[b3] + accV0; n1 = v[b3 + 1] + accV1; n2 = v[b3 + 2] + accV2;
    vnew[b3] = n0; vnew[b3 + 1] = n1; vnew[b3 + 2] = n2;
    size_t b1 = (size_t)i * 128 + f;
    float sv = s[b1] + accS;
    snew[b1] = sv;
    SN[f] = bf2f(f2bf(sv));                   // bf16-rounded, matches old snbf
  }
  __syncthreads();

  // fused hidden GEMV: h[f] = ssp(SN . wu1[f,:] + bu1[f]), split-K over the
  // (split) wave pairs; SN reads are wave-uniform addresses (broadcast).
  float hp = 0.f;
  {
    const int k0 = split * 64;
    const unsigned short* wr = wu1 + (size_t)f * 128 + k0;
#pragma unroll
    for (int kk = 0; kk < 8; kk++) {
      short8 w8 = *(const short8*)(wr + kk * 8);
      float4 sa = *(const float4*)&SN[k0 + kk * 8];
      float4 sb = *(const float4*)&SN[k0 + kk * 8 + 4];
      hp = fmaf(bf2f((unsigned short)w8[0]), sa.x, hp);
      hp = fmaf(bf2f((unsigned short)w8[1]), sa.y, hp);
      hp = fmaf(bf2f((unsigned short)w8[2]), sa.z, hp);
      hp = fmaf(bf2f((unsigned short)w8[3]), sa.w, hp);
      hp = fmaf(bf2f((unsigned short)w8[4]), sb.x, hp);
      hp = fmaf(bf2f((unsigned short)w8[5]), sb.y, hp);
      hp = fmaf(bf2f((unsigned short)w8[6]), sb.z, hp);
      hp = fmaf(bf2f((unsigned short)w8[7]), sb.w, hp);
    }
  }
  if (split == 1) PH[f] = hp;
  __syncthreads();
  if (split == 0) {
    float h = hp + PH[f] + bu1[f];
    float sp = (h > 15.f) ? h : log1pf(__expf(h));
    sp -= 0.69314718056f;
    us4 o; o.x = f2bf(n0); o.y = f2bf(n1); o.z = f2bf(n2); o.w = f2bf(sp);
    vnew4[(size_t)i * 128 + f] = o;
  }
}

// ---------------------------------------------------------------------------
// pass 2 (aggregation + fused final): block = 1 dst node, 4 waves =
// (feature half) x (edge parity). Gathers 8B {vx,vy,vz,h}; epilogue does
// s_mean = hmean@us2^T + b2 (split-K dots, z-masked for deg==0), norm, and
// writes vout/sout directly.
__global__ __launch_bounds__(256, 4) void pass2_kernel(
    const us4* __restrict__ vnew4,    // [N+1,128] {vx,vy,vz,h}
    const int* __restrict__ jbuf, const int* __restrict__ deg,
    const unsigned short* __restrict__ W2,   // [384][128] bf16 (w_us2)
    const float* __restrict__ B2,            // [384] (us2_b)
    const float* __restrict__ vnew,          // [N,384] fp32
    const float* __restrict__ snew,          // [N,128] fp32
    float* __restrict__ vout, float* __restrict__ sout, int nNodes)
{
  __shared__ float red[512];
  __shared__ float HM[128];                  // hmean (bf16-rounded) broadcast
  __shared__ float PP[384];                  // s_mean dot partials

  const int wave = threadIdx.x >> 6, lane = threadIdx.x & 63;
  const int half = wave >> 1, split = wave & 1;
  const int i = blockIdx.x;
  const int f = lane + 64 * half;

  int cnt = deg[i]; if (cnt > CAP) cnt = CAP;
  const int base = i * CAP;
  int jv = (lane < cnt) ? jbuf[base + lane] : nNodes;   // dummy row for pads

  float accU0 = 0.f, accU1 = 0.f, accU2 = 0.f, accH = 0.f;

  for (int b0 = split; b0 < cnt; b0 += 16) {
    us4 cb[8];
#pragma unroll
    for (int k = 0; k < 8; k++) {
      int e = b0 + 2 * k;
      int ec = (e < 63) ? e : 63;              // lane 63 holds dummy when e>=cnt
      int j = __shfl(jv, ec);
      cb[k] = vnew4[(size_t)j * 128 + f];
    }
#pragma unroll
    for (int k = 0; k < 8; k++) {
      int e = b0 + 2 * k;
      if (e < cnt) {                           // wave-uniform guard
        accU0 += bf2f(cb[k].x);
        accU1 += bf2f(cb[k].y);
        accU2 += bf2f(cb[k].z);
        accH  += bf2f(cb[k].w);
      }
    }
  }

  const int idx = half * 64 + lane;           // == f
  if (split == 1) {
    red[idx * 4 + 0] = accU0; red[idx * 4 + 1] = accU1;
    red[idx * 4 + 2] = accU2; red[idx * 4 + 3] = accH;
  }
  __syncthreads();
  float uv0 = 0.f, uv1 = 0.f, uv2 = 0.f;
  if (split == 0) {
    accU0 += red[idx * 4 + 0]; accU1 += red[idx * 4 + 1];
    accU2 += red[idx * 4 + 2]; accH  += red[idx * 4 + 3];
    float dinv = 1.0f / (float)(cnt > 0 ? cnt : 1);
    uv0 = accU0 * dinv; uv1 = accU1 * dinv; uv2 = accU2 * dinv;
    HM[f] = bf2f(f2bf(accH * dinv));          // bf16-rounded, matches old hmean
  }
  __syncthreads();

  // fused s_mean GEMV: 3 rows per feature-thread, split-K over wave pairs.
  float pa = 0.f, pb = 0.f, pc = 0.f;
  {
    const int k0 = split * 64;
#pragma unroll
    for (int kk = 0; kk < 8; kk++) {
      short8 wa = *(const short8*)(W2 + (size_t)f * 128 + k0 + kk * 8);
      short8 wb = *(const short8*)(W2 + (size_t)(128 + f) * 128 + k0 + kk * 8);
      short8 wc = *(const short8*)(W2 + (size_t)(256 + f) * 128 + k0 + kk * 8);
      float4 sa = *(const float4*)&HM[k0 + kk * 8];
      float4 sb = *(const float4*)&HM[k0 + kk * 8 + 4];
      float hv0 = sa.x, hv1 = sa.y, hv2 = sa.z, hv3 = sa.w;
      float hv4 = sb.x, hv5 = sb.y, hv6 = sb.z, hv7 = sb.w;
      pa = fmaf(bf2f((unsigned short)wa[0]), hv0, pa);
      pa = fmaf(bf2f((unsigned short)wa[1]), hv1, pa);
      pa = fmaf(bf2f((unsigned short)wa[2]), hv2, pa);
      pa = fmaf(bf2f((unsigned short)wa[3]), hv3, pa);
      pa = fmaf(bf2f((unsigned short)wa[4]), hv4, pa);
      pa = fmaf(bf2f((unsigned short)wa[5]), hv5, pa);
      pa = fmaf(bf2f((unsigned short)wa[6]), hv6, pa);
      pa = fmaf(bf2f((unsigned short)wa[7]), hv7, pa);
      pb = fmaf(bf2f((unsigned short)wb[0]), hv0, pb);
      pb = fmaf(bf2f((unsigned short)wb[1]), hv1, pb);
      pb = fmaf(bf2f((unsigned short)wb[2]), hv2, pb);
      pb = fmaf(bf2f((unsigned short)wb[3]), hv3, pb);
      pb = fmaf(bf2f((unsigned short)wb[4]), hv4, pb);
      pb = fmaf(bf2f((unsigned short)wb[5]), hv5, pb);
      pb = fmaf(bf2f((unsigned short)wb[6]), hv6, pb);
      pb = fmaf(bf2f((unsigned short)wb[7]), hv7, pb);
      pc = fmaf(bf2f((unsigned short)wc[0]), hv0, pc);
      pc = fmaf(bf2f((unsigned short)wc[1]), hv1, pc);
      pc = fmaf(bf2f((unsigned short)wc[2]), hv2, pc);
      pc = fmaf(bf2f((unsigned short)wc[3]), hv3, pc);
      pc = fmaf(bf2f((unsigned short)wc[4]), hv4, pc);
      pc = fmaf(bf2f((unsigned short)wc[5]), hv5, pc);
      pc = fmaf(bf2f((unsigned short)wc[6]), hv6, pc);
      pc = fmaf(bf2f((unsigned short)wc[7]), hv7, pc);
    }
  }
  if (split == 1) { PP[f] = pa; PP[128 + f] = pb; PP[256 + f] = pc; }
  __syncthreads();
  if (split == 0) {
    float z = (cnt > 0) ? 1.f : 0.f;          // ref: s_mean = 0 for deg==0
    float avv = (pa + PP[f]       + B2[f])       * z;
    float asv = (pb + PP[128 + f] + B2[128 + f]) * z;
    float ass = (pc + PP[256 + f] + B2[256 + f]) * z;
    float q = uv0 * uv0 + uv1 * uv1 + uv2 * uv2;
    float ds2 = (q / (q + 1e-5f)) * asv + ass;
    size_t b3 = (size_t)i * 384 + f * 3;
    vout[b3]     = vnew[b3]     + uv0 * avv;
    vout[b3 + 1] = vnew[b3 + 1] + uv1 * avv;
    vout[b3 + 2] = vnew[b3 + 2] + uv2 * avv;
    size_t b1i = (size_t)i * 128 + f;
    sout[b1i] = snew[b1i] + ds2;
  }
}

// ---------------------------------------------------------------------------
extern "C" void kernel_launch(void* const* d_in, const int* in_sizes, int n_in,
                              void* d_out, int out_size, void* d_ws, size_t ws_size,
                              hipStream_t stream)
{
  const float* x     = (const float*)d_in[0];
  const float* v     = (const float*)d_in[1];
  const float* s     = (const float*)d_in[2];
  const float* ms1_w = (const float*)d_in[3];
  const float* ms1_b = (const float*)d_in[4];
  const float* ms2_w = (const float*)d_in[5];
  const float* ms2_b = (const float*)d_in[6];
  const float* mv_w  = (const float*)d_in[7];
  const float* mv_b  = (const float*)d_in[8];
  const float* us1_w = (const float*)d_in[9];
  const float* us1_b = (const float*)d_in[10];
  const float* us2_w = (const float*)d_in[11];
  const float* us2_b = (const float*)d_in[12];
  const int*   src   = (const int*)d_in[13];
  const int*   dst   = (const int*)d_in[14];

  const int N = in_sizes[0] / 3;        // 10000
  const int E = in_sizes[13];           // 100000

  char* p = (char*)d_ws;
  auto alloc = [&](size_t bytes) -> void* {
    void* r = (void*)p;
    p += (bytes + 255) & ~(size_t)255;
    return r;
  };
  unsigned short* sbf   = (unsigned short*)alloc((size_t)N * 128 * 2);
  unsigned short* w_ms1 = (unsigned short*)alloc(16384 * 2);
  unsigned short* w_ms2 = (unsigned short*)alloc(49152 * 2);
  unsigned short* w_us1 = (unsigned short*)alloc(16384 * 2);
  unsigned short* w_us2 = (unsigned short*)alloc(49152 * 2);
  unsigned short* mvwB  = (unsigned short*)alloc(384 * 32 * 2);
  us4*   v4     = (us4*)alloc((size_t)N * 128 * 8);
  us4*   vnew4  = (us4*)alloc((size_t)(N + 1) * 128 * 8);
  unsigned short* combo1 = (unsigned short*)alloc((size_t)(N + 1) * 128 * 12);
  float* vnew   = (float*)alloc((size_t)N * 384 * 4);
  float* snew   = (float*)alloc((size_t)N * 128 * 4);
  int* cursor   = (int*)alloc((size_t)N * 4);           // becomes deg after fill
  int* jbuf     = (int*)alloc((size_t)N * CAP * 4);

  hipMemsetAsync(cursor, 0, (size_t)N * 4, stream);

  cast_fill_kernel<<<(N * 128 + 255) / 256, 256, 0, stream>>>(
      ms1_w, w_ms1, ms2_w, w_ms2, us1_w, w_us1, us2_w, w_us2,
      s, sbf, v, v4, mv_w, mvwB, src, dst, cursor, jbuf,
      combo1 + (size_t)N * 768, (unsigned short*)(vnew4 + (size_t)N * 128),
      N * 128, E);

  // combo1 = {phi triplet, v triplet}
  mlp_kernel<<<N / 16, 512, 0, stream>>>(sbf, w_ms1, ms1_b, w_ms2, ms2_b,
                                         v4, combo1);

  // pass1 + fused hidden: writes vnew, snew, vnew4{v,h}
  pass1_kernel<<<N, 256, 0, stream>>>(x, combo1, v, s, mvwB, mv_b,
                                      w_us1, us1_b, jbuf, cursor,
                                      vnew, vnew4, snew, N);

  float* vout = (float*)d_out;
  float* sout = vout + (size_t)N * 384;
  // pass2 + fused final: writes vout, sout
  pass2_kernel<<<N, 256, 0, stream>>>(vnew4, jbuf, cursor, w_us2, us2_b,
                                      vnew, snew, vout, sout, N);
}

// Round 5
// 239.148 us; speedup vs baseline: 1.7356x; 1.7356x over previous
//
#include <hip/hip_runtime.h>
#include <hip/hip_bf16.h>

// TMDConv (PaiNN/TorchMD-style) two-pass message passing on MI355X.
// R16 changes vs R15 (R15: 415us REGRESSION — fused GEMVs read weights
// row-per-thread at 256B stride = 64 cache lines per wave-load -> L1
// transaction serialization, pass2 215us w/ VALU 15% HBM 4% = pure stall):
//  - Weights for the fused GEMVs transpose-packed at cast_fill time into
//    [k/8][f][8] bf16 so thread f loads contiguous short8 per 8-k chunk;
//    consecutive lanes 16B apart -> coalesced 1KB/wave-load.
//    w_us1/w_us2 are ONLY consumed by the GEMVs, so layout change is free.
//  - Everything else identical to R15 (single change, clean attribution).

#define F_DIM   128
#define F3_DIM  384
#define L_DIM   20
#define CAP     64          // max in-degree bucket capacity
#define BATCH   16

typedef __attribute__((ext_vector_type(8))) short short8;
typedef __attribute__((ext_vector_type(4))) float f32x4;
typedef __attribute__((ext_vector_type(4))) unsigned short us4;

struct u3 { unsigned a, b, c; };   // 12B record (dwordx3)

__device__ __forceinline__ unsigned short f2bf(float f) {
  union { float f; unsigned u; } a; a.f = f;
  unsigned u = a.u;
  u = (u + 0x7FFFu + ((u >> 16) & 1u)) >> 16;   // RNE
  return (unsigned short)u;
}
__device__ __forceinline__ float bf2f(unsigned short u) {
  union { unsigned u; float f; } a; a.u = ((unsigned)u) << 16;
  return a.f;
}

// ---------------------------------------------------------------------------
// fused cast+fill kernel (+ zeroing of combo1 / vnew4 pad rows)
// w_us1 layout: [k/8][f][8]  (16 x 128 x 8 ushorts)  — GEMV-coalesced
// w_us2 layout: [k/8][of][8] (16 x 384 x 8 ushorts)  — GEMV-coalesced
__global__ __launch_bounds__(256) void cast_fill_kernel(
    const float* __restrict__ ms1_w, unsigned short* __restrict__ w_ms1,
    const float* __restrict__ ms2_w, unsigned short* __restrict__ w_ms2,
    const float* __restrict__ us1_w, unsigned short* __restrict__ w_us1,
    const float* __restrict__ us2_w, unsigned short* __restrict__ w_us2,
    const float* __restrict__ s,     unsigned short* __restrict__ sbf,
    const float* __restrict__ v,     us4* __restrict__ v4,
    const float* __restrict__ mv_w,  unsigned short* __restrict__ mvwB,
    const int* __restrict__ src, const int* __restrict__ dst,
    int* __restrict__ cursor, int* __restrict__ jbuf,
    unsigned short* __restrict__ c1pad, unsigned short* __restrict__ v4pad,
    int nF, int E)
{
  int i = blockIdx.x * 256 + threadIdx.x;
  if (i < 16384) w_ms1[i] = f2bf(ms1_w[i]);
  if (i < 49152) w_ms2[i] = f2bf(ms2_w[i]);
  if (i < 16384) {                 // us1_w[f][k] -> [k/8][f][8]
    int fo = i >> 7, k = i & 127;
    w_us1[(k >> 3) * 1024 + fo * 8 + (k & 7)] = f2bf(us1_w[i]);
  }
  if (i < 49152) {                 // us2_w[of][k] -> [k/8][of][8]
    int of = i >> 7, k = i & 127;
    w_us2[(k >> 3) * 3072 + of * 8 + (k & 7)] = f2bf(us2_w[i]);
  }
  if (i < nF)    sbf[i] = f2bf(s[i]);
  if (i < nF) {
    const float* vp = v + (size_t)i * 3;
    us4 o; o.x = f2bf(vp[0]); o.y = f2bf(vp[1]); o.z = f2bf(vp[2]); o.w = 0;
    v4[i] = o;
  }
  if (i < 384 * 32) {
    int o = i >> 5, k = i & 31;
    float val = (k < 20) ? mv_w[o * 20 + k] * 0.6324555320336759f : 0.f;
    mvwB[i] = f2bf(val);
  }
  if (i < 768) c1pad[i] = 0;   // combo1 dummy row (pad loads, values unread)
  if (i < 512) v4pad[i] = 0;   // vnew4  dummy row
  if (i < E) {
    int d = dst[i];
    int p = atomicAdd(&cursor[d], 1);
    if (p < CAP) jbuf[d * CAP + p] = src[i];
  }
}

// ---------------------------------------------------------------------------
// Yc[n][f] (12B) = { (ssp(X@W1^T+b1)@W2^T+b2) triplet , Vin[n][f] triplet }
// 8 waves per block, 16 nodes per block; wave w owns feature-tile t = w.
__global__ __launch_bounds__(512) void mlp_kernel(
    const unsigned short* __restrict__ X,    // [n][128] bf16
    const unsigned short* __restrict__ W1,   // [128][128] bf16
    const float* __restrict__ B1,            // [128]
    const unsigned short* __restrict__ W2,   // [384][128] bf16
    const float* __restrict__ B2,            // [384]
    const us4* __restrict__ Vin,             // [n][128] bf16 triplet
    unsigned short* __restrict__ Yc)         // [n][128] 12B records
{
  __shared__ float HT[128 * 17];
  const int lane = threadIdx.x & 63;
  const int wave = threadIdx.x >> 6;         // 0..7 = feature tile
  const int c    = lane & 15;
  const int quad = lane >> 4;
  const int m0   = blockIdx.x * 16;

  // GEMM1: this wave's single output tile t = wave
  f32x4 acc = (f32x4){0.f, 0.f, 0.f, 0.f};
#pragma unroll
  for (int kk = 0; kk < 4; kk++) {
    short8 a = *(const short8*)(X + (size_t)(m0 + c) * 128 + kk * 32 + quad * 8);
    short8 b = *(const short8*)(W1 + (size_t)(wave * 16 + c) * 128 + kk * 32 + quad * 8);
    acc = __builtin_amdgcn_mfma_f32_16x16x32_bf16(a, b, acc, 0, 0, 0);
  }
  {
    int k = wave * 16 + c;
    float bias = B1[k];
#pragma unroll
    for (int r = 0; r < 4; r++) {
      float h = acc[r] + bias;
      float sp = (h > 15.f) ? h : log1pf(__expf(h));
      sp -= 0.69314718056f;
      HT[k * 17 + quad * 4 + r] = sp;
    }
  }
  __syncthreads();

  // GEMM2: 3 tiles (g=0..2) at t = wave, so the 12B record write stays fused
  f32x4 acc2[3];
#pragma unroll
  for (int g = 0; g < 3; g++) acc2[g] = (f32x4){0.f, 0.f, 0.f, 0.f};
#pragma unroll
  for (int kk = 0; kk < 4; kk++) {
    short8 afr;
#pragma unroll
    for (int j = 0; j < 8; j++) {
      float hv = HT[(kk * 32 + quad * 8 + j) * 17 + c];
      afr[j] = (short)f2bf(hv);
    }
#pragma unroll
    for (int g = 0; g < 3; g++) {
      short8 b = *(const short8*)(W2 + (size_t)(g * 128 + wave * 16 + c) * 128 + kk * 32 + quad * 8);
      acc2[g] = __builtin_amdgcn_mfma_f32_16x16x32_bf16(afr, b, acc2[g], 0, 0, 0);
    }
  }
  {
    int f = wave * 16 + c;                   // feature in [0,128)
    float b0 = B2[f], b1 = B2[128 + f], b2 = B2[256 + f];
#pragma unroll
    for (int r = 0; r < 4; r++) {
      int m = quad * 4 + r;
      us4 vv = Vin[(size_t)(m0 + m) * 128 + f];
      unsigned p0 = f2bf(acc2[0][r] + b0);
      unsigned p1 = f2bf(acc2[1][r] + b1);
      unsigned p2 = f2bf(acc2[2][r] + b2);
      u3 rec;
      rec.a = p0 | (p1 << 16);
      rec.b = p2 | ((unsigned)vv.x << 16);
      rec.c = (unsigned)vv.y | ((unsigned)vv.z << 16);
      *(u3*)(Yc + ((size_t)(m0 + m) * 128 + f) * 6) = rec;
    }
  }
}

// ---------------------------------------------------------------------------
// pass 1 (fused W-GEMM + fused hidden GEMV): block = 1 dst node,
// 4 waves = (feature half) x (edge parity). Epilogue computes
// h = ssp(snew@us1^T+b1) via LDS-broadcast split-K dot (coalesced T8
// weights) and writes the full vnew4 record {v0,v1,v2,h}.
__global__ __launch_bounds__(256, 4) void pass1_kernel(
    const float* __restrict__ x,       // [N,3]
    const unsigned short* __restrict__ combo1, // [N+1,128] 12B {phi012,v012}
    const float* __restrict__ v,       // [N,128,3] fp32 (epilogue add)
    const float* __restrict__ s,       // [N,128]
    const unsigned short* __restrict__ mvwB,  // [384][32] bf16 scale-folded
    const float* __restrict__ mv_b,           // [384]
    const unsigned short* __restrict__ wu1,   // [k/8][f][8] bf16 (us1_w T8)
    const float* __restrict__ bu1,            // [128] (us1_b)
    const int* __restrict__ jbuf,      // [N,CAP] src ids
    const int* __restrict__ deg,
    float* __restrict__ vnew, us4* __restrict__ vnew4,
    float* __restrict__ snew, int nNodes)
{
  __shared__ unsigned short Asn[BATCH * 32];  // 1 KB  A-tile (bf16 sn rows)
  __shared__ float4 Au[BATCH];                // 256 B {u0,u1,u2,invr}
  __shared__ us4 Wl[BATCH * 128];             // 16 KB per-batch weight triplets
  __shared__ float red[512];                  // 2 KB  cross-wave reduction
  __shared__ float SN[128];                   // snew (bf16-rounded) broadcast
  __shared__ float PH[128];                   // hidden-dot partials

  const int tid  = threadIdx.x;
  const int wave = tid >> 6, lane = tid & 63;
  const int half = wave >> 1, split = wave & 1;
  const int i = blockIdx.x;
  const int f = lane + 64 * half;             // feature in [0,128)
  const int c = lane & 15, quad = lane >> 4;

  int cnt = deg[i]; if (cnt > CAP) cnt = CAP;
  const int base = i * CAP;

  // B-frags + bias for this wave's 6 tiles: {2w,2w+1,2w+8,2w+9,2w+16,2w+17}
  short8 bfr[6]; float bias[6];
#pragma unroll
  for (int p = 0; p < 3; p++)
#pragma unroll
    for (int h = 0; h < 2; h++) {
      int t = 2 * wave + h + 8 * p;
      bfr[p * 2 + h]  = *(const short8*)(mvwB + (size_t)(t * 16 + c) * 32 + quad * 8);
      bias[p * 2 + h] = mv_b[t * 16 + c];
    }

  const float xi0 = x[i * 3], xi1 = x[i * 3 + 1], xi2 = x[i * 3 + 2];
  int jv = (lane < cnt) ? jbuf[base + lane] : nNodes;   // dummy row for pads

  float accV0 = 0.f, accV1 = 0.f, accV2 = 0.f, accS = 0.f;

  for (int bs = 0; bs < cnt; bs += BATCH) {
    int bcnt = cnt - bs; if (bcnt > BATCH) bcnt = BATCH;
    __syncthreads();                           // previous batch fully consumed

    if (wave == 0) {
      // ALL 64 lanes execute the shfl (source lanes must be exec-active);
      // e = bs + (lane&15) <= 48+15 = 63, always a valid source lane.
      int t16 = lane & (BATCH - 1);
      int e = bs + t16;
      int j = __shfl(jv, e);
      if (lane < BATCH && e < cnt) {
        float d0 = x[j * 3]     - xi0;
        float d1 = x[j * 3 + 1] - xi1;
        float d2 = x[j * 3 + 2] - xi2;
        float r = sqrtf(d0 * d0 + d1 * d1 + d2 * d2 + 1e-5f);
        float invr = 1.0f / r;
        Au[lane] = make_float4(d0 * invr, d1 * invr, d2 * invr, invr);
        float theta = r * 0.6283185307179586f;
        float s1, c1;
        __sincosf(theta, &s1, &c1);
        float c2 = 2.f * c1;
        float pm2 = s1, pm1 = c2 * s1;
        Asn[lane * 32 + 0] = f2bf(pm2);
        Asn[lane * 32 + 1] = f2bf(pm1);
#pragma unroll
        for (int l = 2; l < L_DIM; l++) {
          float cur = c2 * pm1 - pm2;
          Asn[lane * 32 + l] = f2bf(cur);
          pm2 = pm1; pm1 = cur;
        }
#pragma unroll
        for (int l = L_DIM; l < 32; l++) Asn[lane * 32 + l] = 0;
        // pad rows (e >= cnt) left uninitialized — they only feed MFMA acc
        // rows that the el<bcnt guards discard.
      }
    }
    __syncthreads();

    // single 16-row MFMA group
    {
      short8 a = *(const short8*)&Asn[c * 32 + quad * 8];
      f32x4 acc[6];
#pragma unroll
      for (int q = 0; q < 6; q++)
        acc[q] = __builtin_amdgcn_mfma_f32_16x16x32_bf16(
            a, bfr[q], (f32x4){0.f, 0.f, 0.f, 0.f}, 0, 0, 0);
#pragma unroll
      for (int r = 0; r < 4; r++) {
        int el = quad * 4 + r;
        if (el < bcnt) {
          float invr = Au[el].w;
#pragma unroll
          for (int h = 0; h < 2; h++) {
            float wp0 = fmaf(acc[h][r],     invr, bias[h]);
            float wp1 = fmaf(acc[2 + h][r], invr, bias[2 + h]);
            float wp2 = fmaf(acc[4 + h][r], invr, bias[4 + h]);
            float w0 = (wp0 < 5.f) ? 0.5f * (__cosf(wp0 * 0.6283185307179586f) + 1.f) : 0.f;
            float w1 = (wp1 < 5.f) ? 0.5f * (__cosf(wp1 * 0.6283185307179586f) + 1.f) : 0.f;
            float w2 = (wp2 < 5.f) ? 0.5f * (__cosf(wp2 * 0.6283185307179586f) + 1.f) : 0.f;
            us4 o; o.x = f2bf(w0); o.y = f2bf(w1); o.z = f2bf(w2); o.w = 0;
            Wl[el * 128 + wave * 32 + h * 16 + c] = o;
          }
        }
      }
    }
    __syncthreads();

    // phase B: loads unconditional/batched (cb stays in registers, pads hit
    // the L1-hot dummy row); unpack+FMA guarded wave-uniformly.
    u3 cb[8];
#pragma unroll
    for (int k = 0; k < 8; k++) {
      int j = __shfl(jv, bs + split + 2 * k);
      cb[k] = *(const u3*)(combo1 + ((size_t)j * 128 + f) * 6);
    }
#pragma unroll
    for (int k = 0; k < 8; k++) {
      int el = split + 2 * k;
      if (el < bcnt) {
        float4 u = Au[el];
        us4 wv = Wl[el * 128 + f];
        float ph0 = bf2f((unsigned short)(cb[k].a & 0xffff));
        float ph1 = bf2f((unsigned short)(cb[k].a >> 16));
        float ph2 = bf2f((unsigned short)(cb[k].b & 0xffff));
        float vx  = bf2f((unsigned short)(cb[k].b >> 16));
        float vy  = bf2f((unsigned short)(cb[k].c & 0xffff));
        float vz  = bf2f((unsigned short)(cb[k].c >> 16));
        float m0 = ph0 * bf2f(wv.x);
        float m1 = ph1 * bf2f(wv.y);
        float m2 = ph2 * bf2f(wv.z);
        accV0 = fmaf(vx, m0, fmaf(m2, u.x, accV0));
        accV1 = fmaf(vy, m0, fmaf(m2, u.y, accV1));
        accV2 = fmaf(vz, m0, fmaf(m2, u.z, accV2));
        accS += m1;
      }
    }
  }

  const int idx = half * 64 + lane;           // == f
  __syncthreads();
  if (split == 1) {
    red[idx * 4 + 0] = accV0; red[idx * 4 + 1] = accV1;
    red[idx * 4 + 2] = accV2; red[idx * 4 + 3] = accS;
  }
  __syncthreads();
  float n0 = 0.f, n1 = 0.f, n2 = 0.f;
  if (split == 0) {
    accV0 += red[idx * 4 + 0]; accV1 += red[idx * 4 + 1];
    accV2 += red[idx * 4 + 2]; accS  += red[idx * 4 + 3];
    size_t b3 = (size_t)i * 384 + f * 3;
    n0 = v[b3] + accV0; n1 = v[b3 + 1] + accV1; n2 = v[b3 + 2] + accV2;
    vnew[b3] = n0; vnew[b3 + 1] = n1; vnew[b3 + 2] = n2;
    size_t b1 = (size_t)i * 128 + f;
    float sv = s[b1] + accS;
    snew[b1] = sv;
    SN[f] = bf2f(f2bf(sv));                   // bf16-rounded, matches old snbf
  }
  __syncthreads();

  // fused hidden GEMV: h[f] = ssp(SN . wu1[f,:] + bu1[f]), split-K over the
  // wave pairs. T8 layout: thread f loads contiguous short8 per 8-k chunk,
  // consecutive lanes 16B apart -> coalesced 1KB/wave-load.
  float hp = 0.f;
  {
    const int k0 = split * 64;
#pragma unroll
    for (int kk = 0; kk < 8; kk++) {
      int k = k0 + kk * 8;
      short8 w8 = *(const short8*)(wu1 + (size_t)(k >> 3) * 1024 + f * 8);
      float4 sa = *(const float4*)&SN[k];
      float4 sb = *(const float4*)&SN[k + 4];
      hp = fmaf(bf2f((unsigned short)w8[0]), sa.x, hp);
      hp = fmaf(bf2f((unsigned short)w8[1]), sa.y, hp);
      hp = fmaf(bf2f((unsigned short)w8[2]), sa.z, hp);
      hp = fmaf(bf2f((unsigned short)w8[3]), sa.w, hp);
      hp = fmaf(bf2f((unsigned short)w8[4]), sb.x, hp);
      hp = fmaf(bf2f((unsigned short)w8[5]), sb.y, hp);
      hp = fmaf(bf2f((unsigned short)w8[6]), sb.z, hp);
      hp = fmaf(bf2f((unsigned short)w8[7]), sb.w, hp);
    }
  }
  if (split == 1) PH[f] = hp;
  __syncthreads();
  if (split == 0) {
    float h = hp + PH[f] + bu1[f];
    float sp = (h > 15.f) ? h : log1pf(__expf(h));
    sp -= 0.69314718056f;
    us4 o; o.x = f2bf(n0); o.y = f2bf(n1); o.z = f2bf(n2); o.w = f2bf(sp);
    vnew4[(size_t)i * 128 + f] = o;
  }
}

// ---------------------------------------------------------------------------
// pass 2 (aggregation + fused final): block = 1 dst node, 4 waves =
// (feature half) x (edge parity). Gathers 8B {vx,vy,vz,h}; epilogue does
// s_mean = hmean@us2^T + b2 (split-K dots, T8-coalesced weights, z-masked
// for deg==0), norm, and writes vout/sout directly.
__global__ __launch_bounds__(256, 4) void pass2_kernel(
    const us4* __restrict__ vnew4,    // [N+1,128] {vx,vy,vz,h}
    const int* __restrict__ jbuf, const int* __restrict__ deg,
    const unsigned short* __restrict__ W2,   // [k/8][of][8] bf16 (us2_w T8)
    const float* __restrict__ B2,            // [384] (us2_b)
    const float* __restrict__ vnew,          // [N,384] fp32
    const float* __restrict__ snew,          // [N,128] fp32
    float* __restrict__ vout, float* __restrict__ sout, int nNodes)
{
  __shared__ float red[512];
  __shared__ float HM[128];                  // hmean (bf16-rounded) broadcast
  __shared__ float PP[384];                  // s_mean dot partials

  const int wave = threadIdx.x >> 6, lane = threadIdx.x & 63;
  const int half = wave >> 1, split = wave & 1;
  const int i = blockIdx.x;
  const int f = lane + 64 * half;

  int cnt = deg[i]; if (cnt > CAP) cnt = CAP;
  const int base = i * CAP;
  int jv = (lane < cnt) ? jbuf[base + lane] : nNodes;   // dummy row for pads

  float accU0 = 0.f, accU1 = 0.f, accU2 = 0.f, accH = 0.f;

  for (int b0 = split; b0 < cnt; b0 += 16) {
    us4 cb[8];
#pragma unroll
    for (int k = 0; k < 8; k++) {
      int e = b0 + 2 * k;
      int ec = (e < 63) ? e : 63;              // lane 63 holds dummy when e>=cnt
      int j = __shfl(jv, ec);
      cb[k] = vnew4[(size_t)j * 128 + f];
    }
#pragma unroll
    for (int k = 0; k < 8; k++) {
      int e = b0 + 2 * k;
      if (e < cnt) {                           // wave-uniform guard
        accU0 += bf2f(cb[k].x);
        accU1 += bf2f(cb[k].y);
        accU2 += bf2f(cb[k].z);
        accH  += bf2f(cb[k].w);
      }
    }
  }

  const int idx = half * 64 + lane;           // == f
  if (split == 1) {
    red[idx * 4 + 0] = accU0; red[idx * 4 + 1] = accU1;
    red[idx * 4 + 2] = accU2; red[idx * 4 + 3] = accH;
  }
  __syncthreads();
  float uv0 = 0.f, uv1 = 0.f, uv2 = 0.f;
  if (split == 0) {
    accU0 += red[idx * 4 + 0]; accU1 += red[idx * 4 + 1];
    accU2 += red[idx * 4 + 2]; accH  += red[idx * 4 + 3];
    float dinv = 1.0f / (float)(cnt > 0 ? cnt : 1);
    uv0 = accU0 * dinv; uv1 = accU1 * dinv; uv2 = accU2 * dinv;
    HM[f] = bf2f(f2bf(accH * dinv));          // bf16-rounded, matches old hmean
  }
  __syncthreads();

  // fused s_mean GEMV: 3 rows per feature-thread, split-K over wave pairs.
  // T8 layout: each of the 3 row-loads is a contiguous short8, lanes 16B
  // apart -> coalesced.
  float pa = 0.f, pb = 0.f, pc = 0.f;
  {
    const int k0 = split * 64;
#pragma unroll
    for (int kk = 0; kk < 8; kk++) {
      int k = k0 + kk * 8;
      const unsigned short* bp = W2 + (size_t)(k >> 3) * 3072;
      short8 wa = *(const short8*)(bp + (size_t)f * 8);
      short8 wb = *(const short8*)(bp + (size_t)(128 + f) * 8);
      short8 wc = *(const short8*)(bp + (size_t)(256 + f) * 8);
      float4 sa = *(const float4*)&HM[k];
      float4 sb = *(const float4*)&HM[k + 4];
      float hv0 = sa.x, hv1 = sa.y, hv2 = sa.z, hv3 = sa.w;
      float hv4 = sb.x, hv5 = sb.y, hv6 = sb.z, hv7 = sb.w;
      pa = fmaf(bf2f((unsigned short)wa[0]), hv0, pa);
      pa = fmaf(bf2f((unsigned short)wa[1]), hv1, pa);
      pa = fmaf(bf2f((unsigned short)wa[2]), hv2, pa);
      pa = fmaf(bf2f((unsigned short)wa[3]), hv3, pa);
      pa = fmaf(bf2f((unsigned short)wa[4]), hv4, pa);
      pa = fmaf(bf2f((unsigned short)wa[5]), hv5, pa);
      pa = fmaf(bf2f((unsigned short)wa[6]), hv6, pa);
      pa = fmaf(bf2f((unsigned short)wa[7]), hv7, pa);
      pb = fmaf(bf2f((unsigned short)wb[0]), hv0, pb);
      pb = fmaf(bf2f((unsigned short)wb[1]), hv1, pb);
      pb = fmaf(bf2f((unsigned short)wb[2]), hv2, pb);
      pb = fmaf(bf2f((unsigned short)wb[3]), hv3, pb);
      pb = fmaf(bf2f((unsigned short)wb[4]), hv4, pb);
      pb = fmaf(bf2f((unsigned short)wb[5]), hv5, pb);
      pb = fmaf(bf2f((unsigned short)wb[6]), hv6, pb);
      pb = fmaf(bf2f((unsigned short)wb[7]), hv7, pb);
      pc = fmaf(bf2f((unsigned short)wc[0]), hv0, pc);
      pc = fmaf(bf2f((unsigned short)wc[1]), hv1, pc);
      pc = fmaf(bf2f((unsigned short)wc[2]), hv2, pc);
      pc = fmaf(bf2f((unsigned short)wc[3]), hv3, pc);
      pc = fmaf(bf2f((unsigned short)wc[4]), hv4, pc);
      pc = fmaf(bf2f((unsigned short)wc[5]), hv5, pc);
      pc = fmaf(bf2f((unsigned short)wc[6]), hv6, pc);
      pc = fmaf(bf2f((unsigned short)wc[7]), hv7, pc);
    }
  }
  if (split == 1) { PP[f] = pa; PP[128 + f] = pb; PP[256 + f] = pc; }
  __syncthreads();
  if (split == 0) {
    float z = (cnt > 0) ? 1.f : 0.f;          // ref: s_mean = 0 for deg==0
    float avv = (pa + PP[f]       + B2[f])       * z;
    float asv = (pb + PP[128 + f] + B2[128 + f]) * z;
    float ass = (pc + PP[256 + f] + B2[256 + f]) * z;
    float q = uv0 * uv0 + uv1 * uv1 + uv2 * uv2;
    float ds2 = (q / (q + 1e-5f)) * asv + ass;
    size_t b3 = (size_t)i * 384 + f * 3;
    vout[b3]     = vnew[b3]     + uv0 * avv;
    vout[b3 + 1] = vnew[b3 + 1] + uv1 * avv;
    vout[b3 + 2] = vnew[b3 + 2] + uv2 * avv;
    size_t b1i = (size_t)i * 128 + f;
    sout[b1i] = snew[b1i] + ds2;
  }
}

// ---------------------------------------------------------------------------
extern "C" void kernel_launch(void* const* d_in, const int* in_sizes, int n_in,
                              void* d_out, int out_size, void* d_ws, size_t ws_size,
                              hipStream_t stream)
{
  const float* x     = (const float*)d_in[0];
  const float* v     = (const float*)d_in[1];
  const float* s     = (const float*)d_in[2];
  const float* ms1_w = (const float*)d_in[3];
  const float* ms1_b = (const float*)d_in[4];
  const float* ms2_w = (const float*)d_in[5];
  const float* ms2_b = (const float*)d_in[6];
  const float* mv_w  = (const float*)d_in[7];
  const float* mv_b  = (const float*)d_in[8];
  const float* us1_w = (const float*)d_in[9];
  const float* us1_b = (const float*)d_in[10];
  const float* us2_w = (const float*)d_in[11];
  const float* us2_b = (const float*)d_in[12];
  const int*   src   = (const int*)d_in[13];
  const int*   dst   = (const int*)d_in[14];

  const int N = in_sizes[0] / 3;        // 10000
  const int E = in_sizes[13];           // 100000

  char* p = (char*)d_ws;
  auto alloc = [&](size_t bytes) -> void* {
    void* r = (void*)p;
    p += (bytes + 255) & ~(size_t)255;
    return r;
  };
  unsigned short* sbf   = (unsigned short*)alloc((size_t)N * 128 * 2);
  unsigned short* w_ms1 = (unsigned short*)alloc(16384 * 2);
  unsigned short* w_ms2 = (unsigned short*)alloc(49152 * 2);
  unsigned short* w_us1 = (unsigned short*)alloc(16384 * 2);
  unsigned short* w_us2 = (unsigned short*)alloc(49152 * 2);
  unsigned short* mvwB  = (unsigned short*)alloc(384 * 32 * 2);
  us4*   v4     = (us4*)alloc((size_t)N * 128 * 8);
  us4*   vnew4  = (us4*)alloc((size_t)(N + 1) * 128 * 8);
  unsigned short* combo1 = (unsigned short*)alloc((size_t)(N + 1) * 128 * 12);
  float* vnew   = (float*)alloc((size_t)N * 384 * 4);
  float* snew   = (float*)alloc((size_t)N * 128 * 4);
  int* cursor   = (int*)alloc((size_t)N * 4);           // becomes deg after fill
  int* jbuf     = (int*)alloc((size_t)N * CAP * 4);

  hipMemsetAsync(cursor, 0, (size_t)N * 4, stream);

  cast_fill_kernel<<<(N * 128 + 255) / 256, 256, 0, stream>>>(
      ms1_w, w_ms1, ms2_w, w_ms2, us1_w, w_us1, us2_w, w_us2,
      s, sbf, v, v4, mv_w, mvwB, src, dst, cursor, jbuf,
      combo1 + (size_t)N * 768, (unsigned short*)(vnew4 + (size_t)N * 128),
      N * 128, E);

  // combo1 = {phi triplet, v triplet}
  mlp_kernel<<<N / 16, 512, 0, stream>>>(sbf, w_ms1, ms1_b, w_ms2, ms2_b,
                                         v4, combo1);

  // pass1 + fused hidden: writes vnew, snew, vnew4{v,h}
  pass1_kernel<<<N, 256, 0, stream>>>(x, combo1, v, s, mvwB, mv_b,
                                      w_us1, us1_b, jbuf, cursor,
                                      vnew, vnew4, snew, N);

  float* vout = (float*)d_out;
  float* sout = vout + (size_t)N * 384;
  // pass2 + fused final: writes vout, sout
  pass2_kernel<<<N, 256, 0, stream>>>(vnew4, jbuf, cursor, w_us2, us2_b,
                                      vnew, snew, vout, sout, N);
}

// Round 6
// 213.347 us; speedup vs baseline: 1.9455x; 1.1209x over previous
//
#include <hip/hip_runtime.h>
#include <hip/hip_bf16.h>

// TMDConv (PaiNN/TorchMD-style) two-pass message passing on MI355X.
// R17 changes vs R16 (R16: 239us — fused VALU GEMVs were the wrong engine:
// pass1 +12us, pass2 ~65us doing 49k MACs/node scalar + 983MB L2 W2 re-reads;
// cross-round algebra: cast_fill+mlp1 ≈ 75-99us hidden budget):
//  - pass1 reverted to R13 form (proven 63.5us): no GEMV, writes snbf +
//    vnew4{v,0}; keeps R16's wave-uniform phase-B guards.
//  - hidden = MFMA GEMM1-only kernel (625 blk x 8 waves), h packed into
//    vnew4.w via full-8B RMW (fixes R14's partial-store defect).
//  - pass2+final fused: 16-node blocks; 8 waves gather 2 nodes each
//    (coalesced 8B records, dummy-row pads, means -> LDS), then W2 GEMM
//    on MFMA (mlp-style) + epilogue. Kills hmean/uv round-trips (~36MB)
//    and one dispatch; W2 read 625x not 10000x.

#define F_DIM   128
#define F3_DIM  384
#define L_DIM   20
#define CAP     64          // max in-degree bucket capacity
#define BATCH   16

typedef __attribute__((ext_vector_type(8))) short short8;
typedef __attribute__((ext_vector_type(4))) float f32x4;
typedef __attribute__((ext_vector_type(4))) unsigned short us4;

struct u3 { unsigned a, b, c; };   // 12B record (dwordx3)

__device__ __forceinline__ unsigned short f2bf(float f) {
  union { float f; unsigned u; } a; a.f = f;
  unsigned u = a.u;
  u = (u + 0x7FFFu + ((u >> 16) & 1u)) >> 16;   // RNE
  return (unsigned short)u;
}
__device__ __forceinline__ float bf2f(unsigned short u) {
  union { unsigned u; float f; } a; a.u = ((unsigned)u) << 16;
  return a.f;
}

// ---------------------------------------------------------------------------
// fused cast+fill kernel (+ zeroing of combo1 / vnew4 pad rows)
__global__ __launch_bounds__(256) void cast_fill_kernel(
    const float* __restrict__ ms1_w, unsigned short* __restrict__ w_ms1,
    const float* __restrict__ ms2_w, unsigned short* __restrict__ w_ms2,
    const float* __restrict__ us1_w, unsigned short* __restrict__ w_us1,
    const float* __restrict__ us2_w, unsigned short* __restrict__ w_us2,
    const float* __restrict__ s,     unsigned short* __restrict__ sbf,
    const float* __restrict__ v,     us4* __restrict__ v4,
    const float* __restrict__ mv_w,  unsigned short* __restrict__ mvwB,
    const int* __restrict__ src, const int* __restrict__ dst,
    int* __restrict__ cursor, int* __restrict__ jbuf,
    unsigned short* __restrict__ c1pad, unsigned short* __restrict__ v4pad,
    int nF, int E)
{
  int i = blockIdx.x * 256 + threadIdx.x;
  if (i < 16384) w_ms1[i] = f2bf(ms1_w[i]);
  if (i < 49152) w_ms2[i] = f2bf(ms2_w[i]);
  if (i < 16384) w_us1[i] = f2bf(us1_w[i]);
  if (i < 49152) w_us2[i] = f2bf(us2_w[i]);
  if (i < nF)    sbf[i] = f2bf(s[i]);
  if (i < nF) {
    const float* vp = v + (size_t)i * 3;
    us4 o; o.x = f2bf(vp[0]); o.y = f2bf(vp[1]); o.z = f2bf(vp[2]); o.w = 0;
    v4[i] = o;
  }
  if (i < 384 * 32) {
    int o = i >> 5, k = i & 31;
    float val = (k < 20) ? mv_w[o * 20 + k] * 0.6324555320336759f : 0.f;
    mvwB[i] = f2bf(val);
  }
  if (i < 768) c1pad[i] = 0;   // combo1 dummy row: 128 x 12B
  if (i < 512) v4pad[i] = 0;   // vnew4  dummy row: 128 x 8B
  if (i < E) {
    int d = dst[i];
    int p = atomicAdd(&cursor[d], 1);
    if (p < CAP) jbuf[d * CAP + p] = src[i];
  }
}

// ---------------------------------------------------------------------------
// Yc[n][f] (12B) = { (ssp(X@W1^T+b1)@W2^T+b2) triplet , Vin[n][f] triplet }
// 8 waves per block, 16 nodes per block; wave w owns feature-tile t = w.
__global__ __launch_bounds__(512) void mlp_kernel(
    const unsigned short* __restrict__ X,    // [n][128] bf16
    const unsigned short* __restrict__ W1,   // [128][128] bf16
    const float* __restrict__ B1,            // [128]
    const unsigned short* __restrict__ W2,   // [384][128] bf16
    const float* __restrict__ B2,            // [384]
    const us4* __restrict__ Vin,             // [n][128] bf16 triplet
    unsigned short* __restrict__ Yc)         // [n][128] 12B records
{
  __shared__ float HT[128 * 17];
  const int lane = threadIdx.x & 63;
  const int wave = threadIdx.x >> 6;         // 0..7 = feature tile
  const int c    = lane & 15;
  const int quad = lane >> 4;
  const int m0   = blockIdx.x * 16;

  // GEMM1: this wave's single output tile t = wave
  f32x4 acc = (f32x4){0.f, 0.f, 0.f, 0.f};
#pragma unroll
  for (int kk = 0; kk < 4; kk++) {
    short8 a = *(const short8*)(X + (size_t)(m0 + c) * 128 + kk * 32 + quad * 8);
    short8 b = *(const short8*)(W1 + (size_t)(wave * 16 + c) * 128 + kk * 32 + quad * 8);
    acc = __builtin_amdgcn_mfma_f32_16x16x32_bf16(a, b, acc, 0, 0, 0);
  }
  {
    int k = wave * 16 + c;
    float bias = B1[k];
#pragma unroll
    for (int r = 0; r < 4; r++) {
      float h = acc[r] + bias;
      float sp = (h > 15.f) ? h : log1pf(__expf(h));
      sp -= 0.69314718056f;
      HT[k * 17 + quad * 4 + r] = sp;
    }
  }
  __syncthreads();

  // GEMM2: 3 tiles (g=0..2) at t = wave, so the 12B record write stays fused
  f32x4 acc2[3];
#pragma unroll
  for (int g = 0; g < 3; g++) acc2[g] = (f32x4){0.f, 0.f, 0.f, 0.f};
#pragma unroll
  for (int kk = 0; kk < 4; kk++) {
    short8 afr;
#pragma unroll
    for (int j = 0; j < 8; j++) {
      float hv = HT[(kk * 32 + quad * 8 + j) * 17 + c];
      afr[j] = (short)f2bf(hv);
    }
#pragma unroll
    for (int g = 0; g < 3; g++) {
      short8 b = *(const short8*)(W2 + (size_t)(g * 128 + wave * 16 + c) * 128 + kk * 32 + quad * 8);
      acc2[g] = __builtin_amdgcn_mfma_f32_16x16x32_bf16(afr, b, acc2[g], 0, 0, 0);
    }
  }
  {
    int f = wave * 16 + c;                   // feature in [0,128)
    float b0 = B2[f], b1 = B2[128 + f], b2 = B2[256 + f];
#pragma unroll
    for (int r = 0; r < 4; r++) {
      int m = quad * 4 + r;
      us4 vv = Vin[(size_t)(m0 + m) * 128 + f];
      unsigned p0 = f2bf(acc2[0][r] + b0);
      unsigned p1 = f2bf(acc2[1][r] + b1);
      unsigned p2 = f2bf(acc2[2][r] + b2);
      u3 rec;
      rec.a = p0 | (p1 << 16);
      rec.b = p2 | ((unsigned)vv.x << 16);
      rec.c = (unsigned)vv.y | ((unsigned)vv.z << 16);
      *(u3*)(Yc + ((size_t)(m0 + m) * 128 + f) * 6) = rec;
    }
  }
}

// ---------------------------------------------------------------------------
// hidden_kernel: h = ssp(snew@us1^T + b1) via MFMA GEMM1 (8 waves x 16
// nodes); writes vnew4[m][f] as a FULL 8B record {v0,v1,v2,h} (read-modify-
// write of the record pass1 wrote — no partial-store RMW).
__global__ __launch_bounds__(512) void hidden_kernel(
    const unsigned short* __restrict__ X,    // [n][128] bf16 (snbf)
    const unsigned short* __restrict__ W1,   // [128][128] bf16 (w_us1)
    const float* __restrict__ B1,            // [128] (us1_b)
    us4* __restrict__ V4)                    // [n][128] {vx,vy,vz,h}
{
  const int lane = threadIdx.x & 63;
  const int wave = threadIdx.x >> 6;         // 0..7 = feature tile
  const int c    = lane & 15;
  const int quad = lane >> 4;
  const int m0   = blockIdx.x * 16;

  f32x4 acc = (f32x4){0.f, 0.f, 0.f, 0.f};
#pragma unroll
  for (int kk = 0; kk < 4; kk++) {
    short8 a = *(const short8*)(X + (size_t)(m0 + c) * 128 + kk * 32 + quad * 8);
    short8 b = *(const short8*)(W1 + (size_t)(wave * 16 + c) * 128 + kk * 32 + quad * 8);
    acc = __builtin_amdgcn_mfma_f32_16x16x32_bf16(a, b, acc, 0, 0, 0);
  }
  int f = wave * 16 + c;
  float bias = B1[f];
#pragma unroll
  for (int r = 0; r < 4; r++) {
    int m = m0 + quad * 4 + r;
    float h = acc[r] + bias;
    float sp = (h > 15.f) ? h : log1pf(__expf(h));
    sp -= 0.69314718056f;
    us4 rec = V4[(size_t)m * 128 + f];       // {v0,v1,v2,0} from pass1
    rec.w = f2bf(sp);
    V4[(size_t)m * 128 + f] = rec;           // full 8B store, coalesced
  }
}

// ---------------------------------------------------------------------------
// pass 1 (fused W-GEMM): block = 1 dst node, 4 waves = (half) x (parity).
// R13 form (no GEMV); keeps R16's wave-uniform phase-B guards.
__global__ __launch_bounds__(256, 4) void pass1_kernel(
    const float* __restrict__ x,       // [N,3]
    const unsigned short* __restrict__ combo1, // [N+1,128] 12B {phi012,v012}
    const float* __restrict__ v,       // [N,128,3] fp32 (epilogue add)
    const float* __restrict__ s,       // [N,128]
    const unsigned short* __restrict__ mvwB,  // [384][32] bf16 scale-folded
    const float* __restrict__ mv_b,           // [384]
    const int* __restrict__ jbuf,      // [N,CAP] src ids
    const int* __restrict__ deg,
    float* __restrict__ vnew, us4* __restrict__ vnew4,
    float* __restrict__ snew, unsigned short* __restrict__ snew_bf, int nNodes)
{
  __shared__ unsigned short Asn[BATCH * 32];  // 1 KB  A-tile (bf16 sn rows)
  __shared__ float4 Au[BATCH];                // 256 B {u0,u1,u2,invr}
  __shared__ us4 Wl[BATCH * 128];             // 16 KB per-batch weight triplets
  __shared__ float red[512];                  // 2 KB  cross-wave reduction

  const int tid  = threadIdx.x;
  const int wave = tid >> 6, lane = tid & 63;
  const int half = wave >> 1, split = wave & 1;
  const int i = blockIdx.x;
  const int f = lane + 64 * half;             // feature in [0,128)
  const int c = lane & 15, quad = lane >> 4;

  int cnt = deg[i]; if (cnt > CAP) cnt = CAP;
  const int base = i * CAP;

  // B-frags + bias for this wave's 6 tiles: {2w,2w+1,2w+8,2w+9,2w+16,2w+17}
  short8 bfr[6]; float bias[6];
#pragma unroll
  for (int p = 0; p < 3; p++)
#pragma unroll
    for (int h = 0; h < 2; h++) {
      int t = 2 * wave + h + 8 * p;
      bfr[p * 2 + h]  = *(const short8*)(mvwB + (size_t)(t * 16 + c) * 32 + quad * 8);
      bias[p * 2 + h] = mv_b[t * 16 + c];
    }

  const float xi0 = x[i * 3], xi1 = x[i * 3 + 1], xi2 = x[i * 3 + 2];
  int jv = (lane < cnt) ? jbuf[base + lane] : nNodes;   // dummy row for pads

  float accV0 = 0.f, accV1 = 0.f, accV2 = 0.f, accS = 0.f;

  for (int bs = 0; bs < cnt; bs += BATCH) {
    int bcnt = cnt - bs; if (bcnt > BATCH) bcnt = BATCH;
    __syncthreads();                           // previous batch fully consumed

    if (wave == 0) {
      // ALL 64 lanes execute the shfl (source lanes must be exec-active);
      // e = bs + (lane&15) <= 48+15 = 63, always a valid source lane.
      int t16 = lane & (BATCH - 1);
      int e = bs + t16;
      int j = __shfl(jv, e);
      if (lane < BATCH && e < cnt) {
        float d0 = x[j * 3]     - xi0;
        float d1 = x[j * 3 + 1] - xi1;
        float d2 = x[j * 3 + 2] - xi2;
        float r = sqrtf(d0 * d0 + d1 * d1 + d2 * d2 + 1e-5f);
        float invr = 1.0f / r;
        Au[lane] = make_float4(d0 * invr, d1 * invr, d2 * invr, invr);
        float theta = r * 0.6283185307179586f;
        float s1, c1;
        __sincosf(theta, &s1, &c1);
        float c2 = 2.f * c1;
        float pm2 = s1, pm1 = c2 * s1;
        Asn[lane * 32 + 0] = f2bf(pm2);
        Asn[lane * 32 + 1] = f2bf(pm1);
#pragma unroll
        for (int l = 2; l < L_DIM; l++) {
          float cur = c2 * pm1 - pm2;
          Asn[lane * 32 + l] = f2bf(cur);
          pm2 = pm1; pm1 = cur;
        }
#pragma unroll
        for (int l = L_DIM; l < 32; l++) Asn[lane * 32 + l] = 0;
        // pad rows (e >= cnt) left uninitialized — they only feed MFMA acc
        // rows that the el<bcnt guards discard.
      }
    }
    __syncthreads();

    // single 16-row MFMA group
    {
      short8 a = *(const short8*)&Asn[c * 32 + quad * 8];
      f32x4 acc[6];
#pragma unroll
      for (int q = 0; q < 6; q++)
        acc[q] = __builtin_amdgcn_mfma_f32_16x16x32_bf16(
            a, bfr[q], (f32x4){0.f, 0.f, 0.f, 0.f}, 0, 0, 0);
#pragma unroll
      for (int r = 0; r < 4; r++) {
        int el = quad * 4 + r;
        if (el < bcnt) {
          float invr = Au[el].w;
#pragma unroll
          for (int h = 0; h < 2; h++) {
            float wp0 = fmaf(acc[h][r],     invr, bias[h]);
            float wp1 = fmaf(acc[2 + h][r], invr, bias[2 + h]);
            float wp2 = fmaf(acc[4 + h][r], invr, bias[4 + h]);
            float w0 = (wp0 < 5.f) ? 0.5f * (__cosf(wp0 * 0.6283185307179586f) + 1.f) : 0.f;
            float w1 = (wp1 < 5.f) ? 0.5f * (__cosf(wp1 * 0.6283185307179586f) + 1.f) : 0.f;
            float w2 = (wp2 < 5.f) ? 0.5f * (__cosf(wp2 * 0.6283185307179586f) + 1.f) : 0.f;
            us4 o; o.x = f2bf(w0); o.y = f2bf(w1); o.z = f2bf(w2); o.w = 0;
            Wl[el * 128 + wave * 32 + h * 16 + c] = o;
          }
        }
      }
    }
    __syncthreads();

    // phase B: loads unconditional/batched (cb stays in registers, pads hit
    // the L1-hot dummy row); unpack+FMA guarded wave-uniformly.
    u3 cb[8];
#pragma unroll
    for (int k = 0; k < 8; k++) {
      int j = __shfl(jv, bs + split + 2 * k);
      cb[k] = *(const u3*)(combo1 + ((size_t)j * 128 + f) * 6);
    }
#pragma unroll
    for (int k = 0; k < 8; k++) {
      int el = split + 2 * k;
      if (el < bcnt) {
        float4 u = Au[el];
        us4 wv = Wl[el * 128 + f];
        float ph0 = bf2f((unsigned short)(cb[k].a & 0xffff));
        float ph1 = bf2f((unsigned short)(cb[k].a >> 16));
        float ph2 = bf2f((unsigned short)(cb[k].b & 0xffff));
        float vx  = bf2f((unsigned short)(cb[k].b >> 16));
        float vy  = bf2f((unsigned short)(cb[k].c & 0xffff));
        float vz  = bf2f((unsigned short)(cb[k].c >> 16));
        float m0 = ph0 * bf2f(wv.x);
        float m1 = ph1 * bf2f(wv.y);
        float m2 = ph2 * bf2f(wv.z);
        accV0 = fmaf(vx, m0, fmaf(m2, u.x, accV0));
        accV1 = fmaf(vy, m0, fmaf(m2, u.y, accV1));
        accV2 = fmaf(vz, m0, fmaf(m2, u.z, accV2));
        accS += m1;
      }
    }
  }

  const int idx = half * 64 + lane;
  __syncthreads();
  if (split == 1) {
    red[idx * 4 + 0] = accV0; red[idx * 4 + 1] = accV1;
    red[idx * 4 + 2] = accV2; red[idx * 4 + 3] = accS;
  }
  __syncthreads();
  if (split == 0) {
    accV0 += red[idx * 4 + 0]; accV1 += red[idx * 4 + 1];
    accV2 += red[idx * 4 + 2]; accS  += red[idx * 4 + 3];
    size_t b3 = (size_t)i * 384 + f * 3;
    float n0 = v[b3] + accV0, n1 = v[b3 + 1] + accV1, n2 = v[b3 + 2] + accV2;
    vnew[b3] = n0; vnew[b3 + 1] = n1; vnew[b3 + 2] = n2;
    us4 o; o.x = f2bf(n0); o.y = f2bf(n1); o.z = f2bf(n2); o.w = 0;
    vnew4[(size_t)i * 128 + f] = o;
    size_t b1 = (size_t)i * 128 + f;
    float sv = s[b1] + accS;
    snew[b1] = sv;
    snew_bf[b1] = f2bf(sv);
  }
}

// ---------------------------------------------------------------------------
// pass 2 + final fused: block = 16 dst nodes, 8 waves.
// Gather phase: wave w gathers edges of nodes {2w, 2w+1}: coalesced 8B
// records {vx,vy,vz,h}; per-node means -> LDS (uv fp32, hmean bf16).
// GEMM phase: s_mean = hmean@us2^T + b2 on MFMA (mlp-style tiles), then
// epilogue (deg==0 z-mask, norm, residual adds) writes vout/sout.
__global__ __launch_bounds__(512, 2) void pass2_kernel(
    const us4* __restrict__ vnew4,    // [N+1,128] {vx,vy,vz,h}
    const int* __restrict__ jbuf, const int* __restrict__ deg,
    const unsigned short* __restrict__ W2,   // [384][128] bf16 (w_us2)
    const float* __restrict__ B2,            // [384] (us2_b)
    const float* __restrict__ vnew,          // [N,384] fp32
    const float* __restrict__ snew,          // [N,128] fp32
    float* __restrict__ vout, float* __restrict__ sout, int nNodes)
{
  __shared__ unsigned short HMb[16][136];    // hmean bf16, padded row stride
  __shared__ float UV[16 * 128 * 3];         // 24 KB uv means

  const int tid  = threadIdx.x;
  const int wave = tid >> 6, lane = tid & 63;
  const int c    = lane & 15, quad = lane >> 4;
  const int m0   = blockIdx.x * 16;

  // ---- gather phase: wave handles block-local nodes ra=2w, rb=2w+1
  const int ra = 2 * wave, rb = ra + 1;
  const int na = m0 + ra, nb = m0 + rb;
  int ca = deg[na]; if (ca > CAP) ca = CAP;
  int cb = deg[nb]; if (cb > CAP) cb = CAP;
  int jva = (lane < ca) ? jbuf[na * CAP + lane] : nNodes;
  int jvb = (lane < cb) ? jbuf[nb * CAP + lane] : nNodes;

  float a0l = 0.f, a1l = 0.f, a2l = 0.f, ahl = 0.f;
  float a0h = 0.f, a1h = 0.f, a2h = 0.f, ahh = 0.f;
  float b0l = 0.f, b1l = 0.f, b2l = 0.f, bhl = 0.f;
  float b0h = 0.f, b1h = 0.f, b2h = 0.f, bhh = 0.f;

  int emax = (ca > cb) ? ca : cb;
  for (int e = 0; e < emax; ++e) {
    // lanes >= cnt hold nNodes, so shfl(jv, e) for e >= cnt yields the
    // zeroed dummy row automatically — no masking needed.
    int ja = __shfl(jva, e);
    int jb = __shfl(jvb, e);
    us4 ral = vnew4[(size_t)ja * 128 + lane];        // coalesced 512B/wave
    us4 rah = vnew4[(size_t)ja * 128 + lane + 64];
    us4 rbl = vnew4[(size_t)jb * 128 + lane];
    us4 rbh = vnew4[(size_t)jb * 128 + lane + 64];
    a0l += bf2f(ral.x); a1l += bf2f(ral.y); a2l += bf2f(ral.z); ahl += bf2f(ral.w);
    a0h += bf2f(rah.x); a1h += bf2f(rah.y); a2h += bf2f(rah.z); ahh += bf2f(rah.w);
    b0l += bf2f(rbl.x); b1l += bf2f(rbl.y); b2l += bf2f(rbl.z); bhl += bf2f(rbl.w);
    b0h += bf2f(rbh.x); b1h += bf2f(rbh.y); b2h += bf2f(rbh.z); bhh += bf2f(rbh.w);
  }

  float dia = 1.0f / (float)(ca > 0 ? ca : 1);
  float dib = 1.0f / (float)(cb > 0 ? cb : 1);
  {
    int fl = lane, fh = lane + 64;
    UV[(ra * 128 + fl) * 3 + 0] = a0l * dia;
    UV[(ra * 128 + fl) * 3 + 1] = a1l * dia;
    UV[(ra * 128 + fl) * 3 + 2] = a2l * dia;
    UV[(ra * 128 + fh) * 3 + 0] = a0h * dia;
    UV[(ra * 128 + fh) * 3 + 1] = a1h * dia;
    UV[(ra * 128 + fh) * 3 + 2] = a2h * dia;
    UV[(rb * 128 + fl) * 3 + 0] = b0l * dib;
    UV[(rb * 128 + fl) * 3 + 1] = b1l * dib;
    UV[(rb * 128 + fl) * 3 + 2] = b2l * dib;
    UV[(rb * 128 + fh) * 3 + 0] = b0h * dib;
    UV[(rb * 128 + fh) * 3 + 1] = b1h * dib;
    UV[(rb * 128 + fh) * 3 + 2] = b2h * dib;
    HMb[ra][fl] = f2bf(ahl * dia);
    HMb[ra][fh] = f2bf(ahh * dia);
    HMb[rb][fl] = f2bf(bhl * dib);
    HMb[rb][fh] = f2bf(bhh * dib);
  }
  __syncthreads();

  // ---- GEMM phase: A row = node c, K = 128 hidden features
  f32x4 acc2[3];
#pragma unroll
  for (int g = 0; g < 3; g++) acc2[g] = (f32x4){0.f, 0.f, 0.f, 0.f};
#pragma unroll
  for (int kk = 0; kk < 4; kk++) {
    short8 afr = *(const short8*)&HMb[c][kk * 32 + quad * 8];
#pragma unroll
    for (int g = 0; g < 3; g++) {
      short8 b = *(const short8*)(W2 + (size_t)(g * 128 + wave * 16 + c) * 128 + kk * 32 + quad * 8);
      acc2[g] = __builtin_amdgcn_mfma_f32_16x16x32_bf16(afr, b, acc2[g], 0, 0, 0);
    }
  }

  int f = wave * 16 + c;
  float bb0 = B2[f], bb1 = B2[128 + f], bb2 = B2[256 + f];
#pragma unroll
  for (int r = 0; r < 4; r++) {
    int m = quad * 4 + r;
    int gm = m0 + m;
    float z = (deg[gm] > 0) ? 1.f : 0.f;     // ref: s_mean = 0 for deg==0
    float avv = (acc2[0][r] + bb0) * z;
    float asv = (acc2[1][r] + bb1) * z;
    float ass = (acc2[2][r] + bb2) * z;
    float uv0 = UV[(m * 128 + f) * 3 + 0];
    float uv1 = UV[(m * 128 + f) * 3 + 1];
    float uv2 = UV[(m * 128 + f) * 3 + 2];
    float q = uv0 * uv0 + uv1 * uv1 + uv2 * uv2;
    float ds2 = (q / (q + 1e-5f)) * asv + ass;
    size_t b3 = (size_t)gm * 384 + f * 3;
    vout[b3]     = vnew[b3]     + uv0 * avv;
    vout[b3 + 1] = vnew[b3 + 1] + uv1 * avv;
    vout[b3 + 2] = vnew[b3 + 2] + uv2 * avv;
    size_t b1i = (size_t)gm * 128 + f;
    sout[b1i] = snew[b1i] + ds2;
  }
}

// ---------------------------------------------------------------------------
extern "C" void kernel_launch(void* const* d_in, const int* in_sizes, int n_in,
                              void* d_out, int out_size, void* d_ws, size_t ws_size,
                              hipStream_t stream)
{
  const float* x     = (const float*)d_in[0];
  const float* v     = (const float*)d_in[1];
  const float* s     = (const float*)d_in[2];
  const float* ms1_w = (const float*)d_in[3];
  const float* ms1_b = (const float*)d_in[4];
  const float* ms2_w = (const float*)d_in[5];
  const float* ms2_b = (const float*)d_in[6];
  const float* mv_w  = (const float*)d_in[7];
  const float* mv_b  = (const float*)d_in[8];
  const float* us1_w = (const float*)d_in[9];
  const float* us1_b = (const float*)d_in[10];
  const float* us2_w = (const float*)d_in[11];
  const float* us2_b = (const float*)d_in[12];
  const int*   src   = (const int*)d_in[13];
  const int*   dst   = (const int*)d_in[14];

  const int N = in_sizes[0] / 3;        // 10000
  const int E = in_sizes[13];           // 100000

  char* p = (char*)d_ws;
  auto alloc = [&](size_t bytes) -> void* {
    void* r = (void*)p;
    p += (bytes + 255) & ~(size_t)255;
    return r;
  };
  unsigned short* sbf   = (unsigned short*)alloc((size_t)N * 128 * 2);
  unsigned short* snbf  = (unsigned short*)alloc((size_t)N * 128 * 2);
  unsigned short* w_ms1 = (unsigned short*)alloc(16384 * 2);
  unsigned short* w_ms2 = (unsigned short*)alloc(49152 * 2);
  unsigned short* w_us1 = (unsigned short*)alloc(16384 * 2);
  unsigned short* w_us2 = (unsigned short*)alloc(49152 * 2);
  unsigned short* mvwB  = (unsigned short*)alloc(384 * 32 * 2);
  us4*   v4     = (us4*)alloc((size_t)N * 128 * 8);
  us4*   vnew4  = (us4*)alloc((size_t)(N + 1) * 128 * 8);
  unsigned short* combo1 = (unsigned short*)alloc((size_t)(N + 1) * 128 * 12);
  float* vnew   = (float*)alloc((size_t)N * 384 * 4);
  float* snew   = (float*)alloc((size_t)N * 128 * 4);
  int* cursor   = (int*)alloc((size_t)N * 4);           // becomes deg after fill
  int* jbuf     = (int*)alloc((size_t)N * CAP * 4);

  hipMemsetAsync(cursor, 0, (size_t)N * 4, stream);

  cast_fill_kernel<<<(N * 128 + 255) / 256, 256, 0, stream>>>(
      ms1_w, w_ms1, ms2_w, w_ms2, us1_w, w_us1, us2_w, w_us2,
      s, sbf, v, v4, mv_w, mvwB, src, dst, cursor, jbuf,
      combo1 + (size_t)N * 768, (unsigned short*)(vnew4 + (size_t)N * 128),
      N * 128, E);

  // combo1 = {phi triplet, v triplet}
  mlp_kernel<<<N / 16, 512, 0, stream>>>(sbf, w_ms1, ms1_b, w_ms2, ms2_b,
                                         v4, combo1);

  // pass1: writes vnew, snew, snbf, vnew4{v,0}
  pass1_kernel<<<N, 256, 0, stream>>>(x, combo1, v, s, mvwB, mv_b,
                                      jbuf, cursor, vnew, vnew4, snew, snbf, N);

  // h = ssp(snew@us1^T+b1) -> vnew4.w (MFMA, full-record RMW)
  hidden_kernel<<<N / 16, 512, 0, stream>>>(snbf, w_us1, us1_b, vnew4);

  float* vout = (float*)d_out;
  float* sout = vout + (size_t)N * 384;
  // pass2 + final fused: 16-node blocks, MFMA for W2
  pass2_kernel<<<N / 16, 512, 0, stream>>>(vnew4, jbuf, cursor, w_us2, us2_b,
                                           vnew, snew, vout, sout, N);
}

// Round 7
// 209.704 us; speedup vs baseline: 1.9793x; 1.0174x over previous
//
#include <hip/hip_runtime.h>
#include <hip/hip_bf16.h>

// TMDConv (PaiNN/TorchMD-style) two-pass message passing on MI355X.
// R18 changes vs R17 (R17: 213.3us best; pass1 57.4us VALU 60% Mfma 2.6% ->
// VALU-issue + staging-barrier bound; 156us invisible pool):
//  - pass1 staging parallelized: 16 threads/edge across ALL 4 waves (was:
//    wave0-only, ~160 serial wave-inst of Chebyshev+f2bf while 3 waves idle
//    at the barrier). Basis sin((l+1)*theta) computed directly per lane
//    (1-2 __sinf each; also closer to ref than the recurrence). Shfl stays
//    unconditional (source-lane rule), guards after.
//  - pass2 gather unrolled x2: 8 independent loads in flight/iter. Odd-tail
//    safe: lane emax>=ca,cb holds nNodes -> zeroed dummy row.
//  - v->v4 pre-cast dropped: mlp_kernel reads v fp32 directly, casts in
//    epilogue (-20.5MB cast_fill traffic, one less buffer).

#define F_DIM   128
#define F3_DIM  384
#define L_DIM   20
#define CAP     64          // max in-degree bucket capacity
#define BATCH   16

typedef __attribute__((ext_vector_type(8))) short short8;
typedef __attribute__((ext_vector_type(4))) float f32x4;
typedef __attribute__((ext_vector_type(4))) unsigned short us4;

struct u3 { unsigned a, b, c; };   // 12B record (dwordx3)

__device__ __forceinline__ unsigned short f2bf(float f) {
  union { float f; unsigned u; } a; a.f = f;
  unsigned u = a.u;
  u = (u + 0x7FFFu + ((u >> 16) & 1u)) >> 16;   // RNE
  return (unsigned short)u;
}
__device__ __forceinline__ float bf2f(unsigned short u) {
  union { unsigned u; float f; } a; a.u = ((unsigned)u) << 16;
  return a.f;
}

// ---------------------------------------------------------------------------
// fused cast+fill kernel (+ zeroing of combo1 / vnew4 pad rows)
__global__ __launch_bounds__(256) void cast_fill_kernel(
    const float* __restrict__ ms1_w, unsigned short* __restrict__ w_ms1,
    const float* __restrict__ ms2_w, unsigned short* __restrict__ w_ms2,
    const float* __restrict__ us1_w, unsigned short* __restrict__ w_us1,
    const float* __restrict__ us2_w, unsigned short* __restrict__ w_us2,
    const float* __restrict__ s,     unsigned short* __restrict__ sbf,
    const float* __restrict__ mv_w,  unsigned short* __restrict__ mvwB,
    const int* __restrict__ src, const int* __restrict__ dst,
    int* __restrict__ cursor, int* __restrict__ jbuf,
    unsigned short* __restrict__ c1pad, unsigned short* __restrict__ v4pad,
    int nF, int E)
{
  int i = blockIdx.x * 256 + threadIdx.x;
  if (i < 16384) w_ms1[i] = f2bf(ms1_w[i]);
  if (i < 49152) w_ms2[i] = f2bf(ms2_w[i]);
  if (i < 16384) w_us1[i] = f2bf(us1_w[i]);
  if (i < 49152) w_us2[i] = f2bf(us2_w[i]);
  if (i < nF)    sbf[i] = f2bf(s[i]);
  if (i < 384 * 32) {
    int o = i >> 5, k = i & 31;
    float val = (k < 20) ? mv_w[o * 20 + k] * 0.6324555320336759f : 0.f;
    mvwB[i] = f2bf(val);
  }
  if (i < 768) c1pad[i] = 0;   // combo1 dummy row: 128 x 12B
  if (i < 512) v4pad[i] = 0;   // vnew4  dummy row: 128 x 8B
  if (i < E) {
    int d = dst[i];
    int p = atomicAdd(&cursor[d], 1);
    if (p < CAP) jbuf[d * CAP + p] = src[i];
  }
}

// ---------------------------------------------------------------------------
// Yc[n][f] (12B) = { (ssp(X@W1^T+b1)@W2^T+b2) triplet , v[n][f] fp32 triplet
// cast inline }. 8 waves per block, 16 nodes; wave w owns feature-tile t = w.
__global__ __launch_bounds__(512) void mlp_kernel(
    const unsigned short* __restrict__ X,    // [n][128] bf16
    const unsigned short* __restrict__ W1,   // [128][128] bf16
    const float* __restrict__ B1,            // [128]
    const unsigned short* __restrict__ W2,   // [384][128] bf16
    const float* __restrict__ B2,            // [384]
    const float* __restrict__ Vfp,           // [n][128][3] fp32
    unsigned short* __restrict__ Yc)         // [n][128] 12B records
{
  __shared__ float HT[128 * 17];
  const int lane = threadIdx.x & 63;
  const int wave = threadIdx.x >> 6;         // 0..7 = feature tile
  const int c    = lane & 15;
  const int quad = lane >> 4;
  const int m0   = blockIdx.x * 16;

  // GEMM1: this wave's single output tile t = wave
  f32x4 acc = (f32x4){0.f, 0.f, 0.f, 0.f};
#pragma unroll
  for (int kk = 0; kk < 4; kk++) {
    short8 a = *(const short8*)(X + (size_t)(m0 + c) * 128 + kk * 32 + quad * 8);
    short8 b = *(const short8*)(W1 + (size_t)(wave * 16 + c) * 128 + kk * 32 + quad * 8);
    acc = __builtin_amdgcn_mfma_f32_16x16x32_bf16(a, b, acc, 0, 0, 0);
  }
  {
    int k = wave * 16 + c;
    float bias = B1[k];
#pragma unroll
    for (int r = 0; r < 4; r++) {
      float h = acc[r] + bias;
      float sp = (h > 15.f) ? h : log1pf(__expf(h));
      sp -= 0.69314718056f;
      HT[k * 17 + quad * 4 + r] = sp;
    }
  }
  __syncthreads();

  // GEMM2: 3 tiles (g=0..2) at t = wave, so the 12B record write stays fused
  f32x4 acc2[3];
#pragma unroll
  for (int g = 0; g < 3; g++) acc2[g] = (f32x4){0.f, 0.f, 0.f, 0.f};
#pragma unroll
  for (int kk = 0; kk < 4; kk++) {
    short8 afr;
#pragma unroll
    for (int j = 0; j < 8; j++) {
      float hv = HT[(kk * 32 + quad * 8 + j) * 17 + c];
      afr[j] = (short)f2bf(hv);
    }
#pragma unroll
    for (int g = 0; g < 3; g++) {
      short8 b = *(const short8*)(W2 + (size_t)(g * 128 + wave * 16 + c) * 128 + kk * 32 + quad * 8);
      acc2[g] = __builtin_amdgcn_mfma_f32_16x16x32_bf16(afr, b, acc2[g], 0, 0, 0);
    }
  }
  {
    int f = wave * 16 + c;                   // feature in [0,128)
    float b0 = B2[f], b1 = B2[128 + f], b2 = B2[256 + f];
#pragma unroll
    for (int r = 0; r < 4; r++) {
      int m = quad * 4 + r;
      const float* vp = Vfp + ((size_t)(m0 + m) * 128 + f) * 3;
      unsigned p0 = f2bf(acc2[0][r] + b0);
      unsigned p1 = f2bf(acc2[1][r] + b1);
      unsigned p2 = f2bf(acc2[2][r] + b2);
      u3 rec;
      rec.a = p0 | (p1 << 16);
      rec.b = p2 | ((unsigned)f2bf(vp[0]) << 16);
      rec.c = (unsigned)f2bf(vp[1]) | ((unsigned)f2bf(vp[2]) << 16);
      *(u3*)(Yc + ((size_t)(m0 + m) * 128 + f) * 6) = rec;
    }
  }
}

// ---------------------------------------------------------------------------
// hidden_kernel: h = ssp(snew@us1^T + b1) via MFMA GEMM1 (8 waves x 16
// nodes); full-8B RMW of the vnew4 record pass1 wrote.
__global__ __launch_bounds__(512) void hidden_kernel(
    const unsigned short* __restrict__ X,    // [n][128] bf16 (snbf)
    const unsigned short* __restrict__ W1,   // [128][128] bf16 (w_us1)
    const float* __restrict__ B1,            // [128] (us1_b)
    us4* __restrict__ V4)                    // [n][128] {vx,vy,vz,h}
{
  const int lane = threadIdx.x & 63;
  const int wave = threadIdx.x >> 6;         // 0..7 = feature tile
  const int c    = lane & 15;
  const int quad = lane >> 4;
  const int m0   = blockIdx.x * 16;

  f32x4 acc = (f32x4){0.f, 0.f, 0.f, 0.f};
#pragma unroll
  for (int kk = 0; kk < 4; kk++) {
    short8 a = *(const short8*)(X + (size_t)(m0 + c) * 128 + kk * 32 + quad * 8);
    short8 b = *(const short8*)(W1 + (size_t)(wave * 16 + c) * 128 + kk * 32 + quad * 8);
    acc = __builtin_amdgcn_mfma_f32_16x16x32_bf16(a, b, acc, 0, 0, 0);
  }
  int f = wave * 16 + c;
  float bias = B1[f];
#pragma unroll
  for (int r = 0; r < 4; r++) {
    int m = m0 + quad * 4 + r;
    float h = acc[r] + bias;
    float sp = (h > 15.f) ? h : log1pf(__expf(h));
    sp -= 0.69314718056f;
    us4 rec = V4[(size_t)m * 128 + f];       // {v0,v1,v2,0} from pass1
    rec.w = f2bf(sp);
    V4[(size_t)m * 128 + f] = rec;           // full 8B store, coalesced
  }
}

// ---------------------------------------------------------------------------
// pass 1 (fused W-GEMM): block = 1 dst node, 4 waves = (half) x (parity).
// Staging parallelized: 16 threads/edge across all 4 waves; basis computed
// directly per lane (no serial Chebyshev, no wave0 bottleneck).
__global__ __launch_bounds__(256, 4) void pass1_kernel(
    const float* __restrict__ x,       // [N,3]
    const unsigned short* __restrict__ combo1, // [N+1,128] 12B {phi012,v012}
    const float* __restrict__ v,       // [N,128,3] fp32 (epilogue add)
    const float* __restrict__ s,       // [N,128]
    const unsigned short* __restrict__ mvwB,  // [384][32] bf16 scale-folded
    const float* __restrict__ mv_b,           // [384]
    const int* __restrict__ jbuf,      // [N,CAP] src ids
    const int* __restrict__ deg,
    float* __restrict__ vnew, us4* __restrict__ vnew4,
    float* __restrict__ snew, unsigned short* __restrict__ snew_bf, int nNodes)
{
  __shared__ unsigned short Asn[BATCH * 32];  // 1 KB  A-tile (bf16 sn rows)
  __shared__ float4 Au[BATCH];                // 256 B {u0,u1,u2,invr}
  __shared__ us4 Wl[BATCH * 128];             // 16 KB per-batch weight triplets
  __shared__ float red[512];                  // 2 KB  cross-wave reduction

  const int tid  = threadIdx.x;
  const int wave = tid >> 6, lane = tid & 63;
  const int half = wave >> 1, split = wave & 1;
  const int i = blockIdx.x;
  const int f = lane + 64 * half;             // feature in [0,128)
  const int c = lane & 15, quad = lane >> 4;

  int cnt = deg[i]; if (cnt > CAP) cnt = CAP;
  const int base = i * CAP;

  // B-frags + bias for this wave's 6 tiles: {2w,2w+1,2w+8,2w+9,2w+16,2w+17}
  short8 bfr[6]; float bias[6];
#pragma unroll
  for (int p = 0; p < 3; p++)
#pragma unroll
    for (int h = 0; h < 2; h++) {
      int t = 2 * wave + h + 8 * p;
      bfr[p * 2 + h]  = *(const short8*)(mvwB + (size_t)(t * 16 + c) * 32 + quad * 8);
      bias[p * 2 + h] = mv_b[t * 16 + c];
    }

  const float xi0 = x[i * 3], xi1 = x[i * 3 + 1], xi2 = x[i * 3 + 2];
  int jv = (lane < cnt) ? jbuf[base + lane] : nNodes;   // dummy row for pads

  float accV0 = 0.f, accV1 = 0.f, accV2 = 0.f, accS = 0.f;

  for (int bs = 0; bs < cnt; bs += BATCH) {
    int bcnt = cnt - bs; if (bcnt > BATCH) bcnt = BATCH;
    __syncthreads();                           // previous batch fully consumed

    // parallel staging: thread group (e = tid>>4, li = tid&15) per edge.
    // Shfl executed by ALL lanes (source-lane rule); index bs+e <= 63.
    {
      int e  = tid >> 4;
      int li = tid & 15;
      int j  = __shfl(jv, bs + e);
      if (e < bcnt) {
        float d0 = x[j * 3]     - xi0;
        float d1 = x[j * 3 + 1] - xi1;
        float d2 = x[j * 3 + 2] - xi2;
        float r = sqrtf(d0 * d0 + d1 * d1 + d2 * d2 + 1e-5f);
        float invr = 1.0f / r;
        if (li == 0) Au[e] = make_float4(d0 * invr, d1 * invr, d2 * invr, invr);
        float theta = r * 0.6283185307179586f;   // pi*r/RC
        // basis n = li+1 (rows 0..15) and n = li+17 (rows 16..19; rest 0)
        Asn[e * 32 + li] = f2bf(__sinf((float)(li + 1) * theta));
        unsigned short hiv = 0;
        if (li < 4) hiv = f2bf(__sinf((float)(li + 17) * theta));
        Asn[e * 32 + 16 + li] = hiv;
        // pad rows (e >= bcnt) left stale — they only feed MFMA acc rows
        // that the el<bcnt guards discard.
      }
    }
    __syncthreads();

    // single 16-row MFMA group
    {
      short8 a = *(const short8*)&Asn[c * 32 + quad * 8];
      f32x4 acc[6];
#pragma unroll
      for (int q = 0; q < 6; q++)
        acc[q] = __builtin_amdgcn_mfma_f32_16x16x32_bf16(
            a, bfr[q], (f32x4){0.f, 0.f, 0.f, 0.f}, 0, 0, 0);
#pragma unroll
      for (int r = 0; r < 4; r++) {
        int el = quad * 4 + r;
        if (el < bcnt) {
          float invr = Au[el].w;
#pragma unroll
          for (int h = 0; h < 2; h++) {
            float wp0 = fmaf(acc[h][r],     invr, bias[h]);
            float wp1 = fmaf(acc[2 + h][r], invr, bias[2 + h]);
            float wp2 = fmaf(acc[4 + h][r], invr, bias[4 + h]);
            float w0 = (wp0 < 5.f) ? 0.5f * (__cosf(wp0 * 0.6283185307179586f) + 1.f) : 0.f;
            float w1 = (wp1 < 5.f) ? 0.5f * (__cosf(wp1 * 0.6283185307179586f) + 1.f) : 0.f;
            float w2 = (wp2 < 5.f) ? 0.5f * (__cosf(wp2 * 0.6283185307179586f) + 1.f) : 0.f;
            us4 o; o.x = f2bf(w0); o.y = f2bf(w1); o.z = f2bf(w2); o.w = 0;
            Wl[el * 128 + wave * 32 + h * 16 + c] = o;
          }
        }
      }
    }
    __syncthreads();

    // phase B: loads unconditional/batched (cb stays in registers, pads hit
    // the L1-hot dummy row); unpack+FMA guarded wave-uniformly.
    u3 cb[8];
#pragma unroll
    for (int k = 0; k < 8; k++) {
      int j = __shfl(jv, bs + split + 2 * k);
      cb[k] = *(const u3*)(combo1 + ((size_t)j * 128 + f) * 6);
    }
#pragma unroll
    for (int k = 0; k < 8; k++) {
      int el = split + 2 * k;
      if (el < bcnt) {
        float4 u = Au[el];
        us4 wv = Wl[el * 128 + f];
        float ph0 = bf2f((unsigned short)(cb[k].a & 0xffff));
        float ph1 = bf2f((unsigned short)(cb[k].a >> 16));
        float ph2 = bf2f((unsigned short)(cb[k].b & 0xffff));
        float vx  = bf2f((unsigned short)(cb[k].b >> 16));
        float vy  = bf2f((unsigned short)(cb[k].c & 0xffff));
        float vz  = bf2f((unsigned short)(cb[k].c >> 16));
        float m0 = ph0 * bf2f(wv.x);
        float m1 = ph1 * bf2f(wv.y);
        float m2 = ph2 * bf2f(wv.z);
        accV0 = fmaf(vx, m0, fmaf(m2, u.x, accV0));
        accV1 = fmaf(vy, m0, fmaf(m2, u.y, accV1));
        accV2 = fmaf(vz, m0, fmaf(m2, u.z, accV2));
        accS += m1;
      }
    }
  }

  const int idx = half * 64 + lane;
  __syncthreads();
  if (split == 1) {
    red[idx * 4 + 0] = accV0; red[idx * 4 + 1] = accV1;
    red[idx * 4 + 2] = accV2; red[idx * 4 + 3] = accS;
  }
  __syncthreads();
  if (split == 0) {
    accV0 += red[idx * 4 + 0]; accV1 += red[idx * 4 + 1];
    accV2 += red[idx * 4 + 2]; accS  += red[idx * 4 + 3];
    size_t b3 = (size_t)i * 384 + f * 3;
    float n0 = v[b3] + accV0, n1 = v[b3 + 1] + accV1, n2 = v[b3 + 2] + accV2;
    vnew[b3] = n0; vnew[b3 + 1] = n1; vnew[b3 + 2] = n2;
    us4 o; o.x = f2bf(n0); o.y = f2bf(n1); o.z = f2bf(n2); o.w = 0;
    vnew4[(size_t)i * 128 + f] = o;
    size_t b1 = (size_t)i * 128 + f;
    float sv = s[b1] + accS;
    snew[b1] = sv;
    snew_bf[b1] = f2bf(sv);
  }
}

// ---------------------------------------------------------------------------
// pass 2 + final fused: block = 16 dst nodes, 8 waves.
// Gather phase: wave w gathers edges of nodes {2w, 2w+1}, unrolled x2 (8
// loads in flight); per-node means -> LDS. GEMM phase: s_mean = hmean@us2^T
// + b2 on MFMA, then epilogue writes vout/sout.
__global__ __launch_bounds__(512, 2) void pass2_kernel(
    const us4* __restrict__ vnew4,    // [N+1,128] {vx,vy,vz,h}
    const int* __restrict__ jbuf, const int* __restrict__ deg,
    const unsigned short* __restrict__ W2,   // [384][128] bf16 (w_us2)
    const float* __restrict__ B2,            // [384] (us2_b)
    const float* __restrict__ vnew,          // [N,384] fp32
    const float* __restrict__ snew,          // [N,128] fp32
    float* __restrict__ vout, float* __restrict__ sout, int nNodes)
{
  __shared__ unsigned short HMb[16][136];    // hmean bf16, padded row stride
  __shared__ float UV[16 * 128 * 3];         // 24 KB uv means

  const int tid  = threadIdx.x;
  const int wave = tid >> 6, lane = tid & 63;
  const int c    = lane & 15, quad = lane >> 4;
  const int m0   = blockIdx.x * 16;

  // ---- gather phase: wave handles block-local nodes ra=2w, rb=2w+1
  const int ra = 2 * wave, rb = ra + 1;
  const int na = m0 + ra, nb = m0 + rb;
  int ca = deg[na]; if (ca > CAP) ca = CAP;
  int cb = deg[nb]; if (cb > CAP) cb = CAP;
  int jva = (lane < ca) ? jbuf[na * CAP + lane] : nNodes;
  int jvb = (lane < cb) ? jbuf[nb * CAP + lane] : nNodes;

  float a0l = 0.f, a1l = 0.f, a2l = 0.f, ahl = 0.f;
  float a0h = 0.f, a1h = 0.f, a2h = 0.f, ahh = 0.f;
  float b0l = 0.f, b1l = 0.f, b2l = 0.f, bhl = 0.f;
  float b0h = 0.f, b1h = 0.f, b2h = 0.f, bhh = 0.f;

  int emax = (ca > cb) ? ca : cb;
  for (int e = 0; e < emax; e += 2) {
    // lanes >= cnt hold nNodes -> zeroed dummy row; for the odd tail,
    // lane e+1 (= emax <= 63) also holds nNodes for both nodes.
    int ja0 = __shfl(jva, e);
    int jb0 = __shfl(jvb, e);
    int ja1 = __shfl(jva, e + 1);
    int jb1 = __shfl(jvb, e + 1);
    us4 r0al = vnew4[(size_t)ja0 * 128 + lane];      // coalesced 512B/wave
    us4 r0ah = vnew4[(size_t)ja0 * 128 + lane + 64];
    us4 r0bl = vnew4[(size_t)jb0 * 128 + lane];
    us4 r0bh = vnew4[(size_t)jb0 * 128 + lane + 64];
    us4 r1al = vnew4[(size_t)ja1 * 128 + lane];
    us4 r1ah = vnew4[(size_t)ja1 * 128 + lane + 64];
    us4 r1bl = vnew4[(size_t)jb1 * 128 + lane];
    us4 r1bh = vnew4[(size_t)jb1 * 128 + lane + 64];
    a0l += bf2f(r0al.x) + bf2f(r1al.x); a1l += bf2f(r0al.y) + bf2f(r1al.y);
    a2l += bf2f(r0al.z) + bf2f(r1al.z); ahl += bf2f(r0al.w) + bf2f(r1al.w);
    a0h += bf2f(r0ah.x) + bf2f(r1ah.x); a1h += bf2f(r0ah.y) + bf2f(r1ah.y);
    a2h += bf2f(r0ah.z) + bf2f(r1ah.z); ahh += bf2f(r0ah.w) + bf2f(r1ah.w);
    b0l += bf2f(r0bl.x) + bf2f(r1bl.x); b1l += bf2f(r0bl.y) + bf2f(r1bl.y);
    b2l += bf2f(r0bl.z) + bf2f(r1bl.z); bhl += bf2f(r0bl.w) + bf2f(r1bl.w);
    b0h += bf2f(r0bh.x) + bf2f(r1bh.x); b1h += bf2f(r0bh.y) + bf2f(r1bh.y);
    b2h += bf2f(r0bh.z) + bf2f(r1bh.z); bhh += bf2f(r0bh.w) + bf2f(r1bh.w);
  }

  float dia = 1.0f / (float)(ca > 0 ? ca : 1);
  float dib = 1.0f / (float)(cb > 0 ? cb : 1);
  {
    int fl = lane, fh = lane + 64;
    UV[(ra * 128 + fl) * 3 + 0] = a0l * dia;
    UV[(ra * 128 + fl) * 3 + 1] = a1l * dia;
    UV[(ra * 128 + fl) * 3 + 2] = a2l * dia;
    UV[(ra * 128 + fh) * 3 + 0] = a0h * dia;
    UV[(ra * 128 + fh) * 3 + 1] = a1h * dia;
    UV[(ra * 128 + fh) * 3 + 2] = a2h * dia;
    UV[(rb * 128 + fl) * 3 + 0] = b0l * dib;
    UV[(rb * 128 + fl) * 3 + 1] = b1l * dib;
    UV[(rb * 128 + fl) * 3 + 2] = b2l * dib;
    UV[(rb * 128 + fh) * 3 + 0] = b0h * dib;
    UV[(rb * 128 + fh) * 3 + 1] = b1h * dib;
    UV[(rb * 128 + fh) * 3 + 2] = b2h * dib;
    HMb[ra][fl] = f2bf(ahl * dia);
    HMb[ra][fh] = f2bf(ahh * dia);
    HMb[rb][fl] = f2bf(bhl * dib);
    HMb[rb][fh] = f2bf(bhh * dib);
  }
  __syncthreads();

  // ---- GEMM phase: A row = node c, K = 128 hidden features
  f32x4 acc2[3];
#pragma unroll
  for (int g = 0; g < 3; g++) acc2[g] = (f32x4){0.f, 0.f, 0.f, 0.f};
#pragma unroll
  for (int kk = 0; kk < 4; kk++) {
    short8 afr = *(const short8*)&HMb[c][kk * 32 + quad * 8];
#pragma unroll
    for (int g = 0; g < 3; g++) {
      short8 b = *(const short8*)(W2 + (size_t)(g * 128 + wave * 16 + c) * 128 + kk * 32 + quad * 8);
      acc2[g] = __builtin_amdgcn_mfma_f32_16x16x32_bf16(afr, b, acc2[g], 0, 0, 0);
    }
  }

  int f = wave * 16 + c;
  float bb0 = B2[f], bb1 = B2[128 + f], bb2 = B2[256 + f];
#pragma unroll
  for (int r = 0; r < 4; r++) {
    int m = quad * 4 + r;
    int gm = m0 + m;
    float z = (deg[gm] > 0) ? 1.f : 0.f;     // ref: s_mean = 0 for deg==0
    float avv = (acc2[0][r] + bb0) * z;
    float asv = (acc2[1][r] + bb1) * z;
    float ass = (acc2[2][r] + bb2) * z;
    float uv0 = UV[(m * 128 + f) * 3 + 0];
    float uv1 = UV[(m * 128 + f) * 3 + 1];
    float uv2 = UV[(m * 128 + f) * 3 + 2];
    float q = uv0 * uv0 + uv1 * uv1 + uv2 * uv2;
    float ds2 = (q / (q + 1e-5f)) * asv + ass;
    size_t b3 = (size_t)gm * 384 + f * 3;
    vout[b3]     = vnew[b3]     + uv0 * avv;
    vout[b3 + 1] = vnew[b3 + 1] + uv1 * avv;
    vout[b3 + 2] = vnew[b3 + 2] + uv2 * avv;
    size_t b1i = (size_t)gm * 128 + f;
    sout[b1i] = snew[b1i] + ds2;
  }
}

// ---------------------------------------------------------------------------
extern "C" void kernel_launch(void* const* d_in, const int* in_sizes, int n_in,
                              void* d_out, int out_size, void* d_ws, size_t ws_size,
                              hipStream_t stream)
{
  const float* x     = (const float*)d_in[0];
  const float* v     = (const float*)d_in[1];
  const float* s     = (const float*)d_in[2];
  const float* ms1_w = (const float*)d_in[3];
  const float* ms1_b = (const float*)d_in[4];
  const float* ms2_w = (const float*)d_in[5];
  const float* ms2_b = (const float*)d_in[6];
  const float* mv_w  = (const float*)d_in[7];
  const float* mv_b  = (const float*)d_in[8];
  const float* us1_w = (const float*)d_in[9];
  const float* us1_b = (const float*)d_in[10];
  const float* us2_w = (const float*)d_in[11];
  const float* us2_b = (const float*)d_in[12];
  const int*   src   = (const int*)d_in[13];
  const int*   dst   = (const int*)d_in[14];

  const int N = in_sizes[0] / 3;        // 10000
  const int E = in_sizes[13];           // 100000

  char* p = (char*)d_ws;
  auto alloc = [&](size_t bytes) -> void* {
    void* r = (void*)p;
    p += (bytes + 255) & ~(size_t)255;
    return r;
  };
  unsigned short* sbf   = (unsigned short*)alloc((size_t)N * 128 * 2);
  unsigned short* snbf  = (unsigned short*)alloc((size_t)N * 128 * 2);
  unsigned short* w_ms1 = (unsigned short*)alloc(16384 * 2);
  unsigned short* w_ms2 = (unsigned short*)alloc(49152 * 2);
  unsigned short* w_us1 = (unsigned short*)alloc(16384 * 2);
  unsigned short* w_us2 = (unsigned short*)alloc(49152 * 2);
  unsigned short* mvwB  = (unsigned short*)alloc(384 * 32 * 2);
  us4*   vnew4  = (us4*)alloc((size_t)(N + 1) * 128 * 8);
  unsigned short* combo1 = (unsigned short*)alloc((size_t)(N + 1) * 128 * 12);
  float* vnew   = (float*)alloc((size_t)N * 384 * 4);
  float* snew   = (float*)alloc((size_t)N * 128 * 4);
  int* cursor   = (int*)alloc((size_t)N * 4);           // becomes deg after fill
  int* jbuf     = (int*)alloc((size_t)N * CAP * 4);

  hipMemsetAsync(cursor, 0, (size_t)N * 4, stream);

  cast_fill_kernel<<<(N * 128 + 255) / 256, 256, 0, stream>>>(
      ms1_w, w_ms1, ms2_w, w_ms2, us1_w, w_us1, us2_w, w_us2,
      s, sbf, mv_w, mvwB, src, dst, cursor, jbuf,
      combo1 + (size_t)N * 768, (unsigned short*)(vnew4 + (size_t)N * 128),
      N * 128, E);

  // combo1 = {phi triplet, v triplet} (v read fp32, cast inline)
  mlp_kernel<<<N / 16, 512, 0, stream>>>(sbf, w_ms1, ms1_b, w_ms2, ms2_b,
                                         v, combo1);

  // pass1: writes vnew, snew, snbf, vnew4{v,0}
  pass1_kernel<<<N, 256, 0, stream>>>(x, combo1, v, s, mvwB, mv_b,
                                      jbuf, cursor, vnew, vnew4, snew, snbf, N);

  // h = ssp(snew@us1^T+b1) -> vnew4.w (MFMA, full-record RMW)
  hidden_kernel<<<N / 16, 512, 0, stream>>>(snbf, w_us1, us1_b, vnew4);

  float* vout = (float*)d_out;
  float* sout = vout + (size_t)N * 384;
  // pass2 + final fused: 16-node blocks, MFMA for W2
  pass2_kernel<<<N / 16, 512, 0, stream>>>(vnew4, jbuf, cursor, w_us2, us2_b,
                                           vnew, snew, vout, sout, N);
}